// Round 5
// baseline (504.208 us; speedup 1.0000x reference)
//
#include <hip/hip_runtime.h>
#include <hip/hip_bf16.h>

typedef unsigned short u16;
typedef __attribute__((ext_vector_type(8))) short bf16x8;   // 8 bf16 in 4 VGPRs
typedef __attribute__((ext_vector_type(4))) float f32x4;

#define DEV static __device__ __forceinline__

#define BB 16
#define NN 1024
#define EE 768
#define HH 12
#define DD 64
#define BN (BB*NN)   // 16384

DEV u16 f2bf(float f){ __hip_bfloat16 h = __float2bfloat16(f); u16 u; __builtin_memcpy(&u, &h, 2); return u; }
DEV float bf2f(u16 u){ __hip_bfloat16 h; __builtin_memcpy(&h, &u, 2); return __bfloat162float(h); }
DEV void split2(float v, u16& hi, u16& lo){ hi = f2bf(v); lo = f2bf(v - bf2f(hi)); }
DEV bf16x8 ld8(const u16* p){ return *(const bf16x8*)p; }
DEV f32x4 mfma16(bf16x8 a, bf16x8 b, f32x4 c){ return __builtin_amdgcn_mfma_f32_16x16x32_bf16(a, b, c, 0, 0, 0); }

union U8 { bf16x8 v; u16 e[8]; ushort4 q[2]; };

// async global->LDS, 16B per lane. LDS dst must be wave-uniform; HW adds lane*16.
DEV void stage16(const u16* g, u16* l){
  __builtin_amdgcn_global_load_lds((const __attribute__((address_space(1))) void*)g,
                                   (__attribute__((address_space(3))) void*)l,
                                   16, 0, 0);
}

// ---------------- prep kernels ----------------

__global__ __launch_bounds__(256) void split_x_k(const float* __restrict__ x,
                                                 u16* __restrict__ xh, u16* __restrict__ xl){
  int i = blockIdx.x*256 + threadIdx.x;          // < 3145728
  const float4 v = ((const float4*)x)[i];
  ushort4 h, l;
  split2(v.x, h.x, l.x);
  split2(v.y, h.y, l.y);
  split2(v.z, h.z, l.z);
  split2(v.w, h.w, l.w);
  ((ushort4*)xh)[i] = h;
  ((ushort4*)xl)[i] = l;
}

// BT1[1536][2304]: col c -> head h=c>>7, group g=(c>>6)&1 (0=Q,1=K), d=c&63.
// k: seg 0 = W_hi, seg 1 = W_lo, seg 2 = W_hi  (pairs with A_ext = [Xh|Xh|Xl]).
// Q scale folds 1/sqrt(D) AND log2(e): flash softmax runs in exp2 domain.
__global__ __launch_bounds__(256) void pack_bt1_k(const float* __restrict__ Wq,
                                                  const float* __restrict__ Wk,
                                                  u16* __restrict__ BT1){
  int i = blockIdx.x*256 + threadIdx.x;          // < 3538944
  int c = i / 2304, k = i - c*2304;
  int seg = (k >= 768) + (k >= 1536);
  int e = k - seg*768;
  int h = c >> 7, g = (c >> 6) & 1, d = c & 63;
  const float* W = g ? Wk : Wq;
  float v = W[((size_t)h*EE + e)*DD + d] * (g ? 1.0f : 0.125f*1.4426950408889634f);
  u16 hi, lo; split2(v, hi, lo);
  BT1[i] = (seg == 1) ? lo : hi;
}

// BT2[768][768]: col c -> h=c>>6, d=c&63; k=e. Plain bf16.
__global__ __launch_bounds__(256) void pack_bt2_k(const float* __restrict__ Wv,
                                                  u16* __restrict__ BT2){
  int i = blockIdx.x*256 + threadIdx.x;          // < 589824
  int c = i / 768, e = i - c*768;
  int h = c >> 6, d = c & 63;
  BT2[i] = f2bf(Wv[((size_t)h*EE + e)*DD + d]);
}

__global__ __launch_bounds__(256) void pack_wo_k(const float* __restrict__ W, u16* __restrict__ Wt){
  int i = blockIdx.x*256 + threadIdx.x;          // < 49152
  int j = i & 63, k = i >> 6;
  Wt[(size_t)j*EE + k] = f2bf(W[i]);
}

// ---------------- big staged GEMM (m97-style 2-phase, 128x128 tile, BK=64) ----------------
template<int KT, int MODE>
__global__ __launch_bounds__(256) void gemm_big_k(const u16* __restrict__ Xh, const u16* __restrict__ Xl,
                                                  const u16* __restrict__ BT,
                                                  u16* __restrict__ O0h, u16* __restrict__ O0l,
                                                  u16* __restrict__ O1h, u16* __restrict__ O1l){
  __shared__ u16 lds[2][2][8192];                // [buf][A/B][128*64] = 64 KB
  constexpr int NB  = (MODE == 0) ? 12 : 6;      // col-tiles
  constexpr int CPX = (MODE == 0) ? 192 : 96;    // blocks per XCD chunk
  constexpr int KE  = KT*64;                     // B K-extent (elems)

  const int flat = blockIdx.x;
  const int swz = (flat & 7)*CPX + (flat >> 3);  // XCD-chunked, bc fastest (A-panel L2 reuse)
  const int rt = swz / NB, bc = swz - rt*NB;
  const int row0 = rt*128, col0 = bc*128;
  const int tid = threadIdx.x;
  const int w = tid >> 6, l = tid & 63, lr = l & 15, lg = l >> 4;
  const int wr = w >> 1, wc = w & 1;
  const int sr = l >> 3, sce = (l & 7)*8;        // staging: row-in-8, col elem

  f32x4 acc[4][4];
  #pragma unroll
  for (int m=0;m<4;++m)
    #pragma unroll
    for (int n=0;n<4;++n) acc[m][n] = f32x4{0.f,0.f,0.f,0.f};

  auto stage = [&](int buf, int kt){
    const u16* asrc = (MODE == 0 && kt >= 24) ? Xl : Xh;
    const int e0 = (MODE == 0) ? (kt - (kt >= 24 ? 24 : (kt >= 12 ? 12 : 0)))*64 : kt*64;
    const u16* ab = asrc + (size_t)row0*EE + e0 + sce;
    const u16* bb = BT + (size_t)col0*KE + kt*64 + sce;
    u16* la = &lds[buf][0][0];
    u16* lb = &lds[buf][1][0];
    #pragma unroll
    for (int j=0;j<4;++j){
      const int it = j*4 + w;                    // 16 sub-blocks of 8 rows
      stage16(ab + (size_t)(it*8 + sr)*EE, la + it*512);
      stage16(bb + (size_t)(it*8 + sr)*KE, lb + it*512);
    }
  };

  stage(0, 0);
  __syncthreads();

  for (int kt=0; kt<KT; ++kt){
    const int buf = kt & 1;
    if (kt + 1 < KT) stage(buf ^ 1, kt + 1);

    const u16* la = &lds[buf][0][0];
    const u16* lb = &lds[buf][1][0];
    bf16x8 af[4][2], bfr[4][2];
    #pragma unroll
    for (int m=0;m<4;++m)
      #pragma unroll
      for (int ks=0;ks<2;++ks)
        af[m][ks] = ld8(la + (wr*64 + m*16 + lr)*64 + ks*32 + lg*8);
    #pragma unroll
    for (int n=0;n<4;++n)
      #pragma unroll
      for (int ks=0;ks<2;++ks)
        bfr[n][ks] = ld8(lb + (wc*64 + n*16 + lr)*64 + ks*32 + lg*8);

    #pragma unroll
    for (int ks=0;ks<2;++ks)
      #pragma unroll
      for (int m=0;m<4;++m)
        #pragma unroll
        for (int n=0;n<4;++n)
          acc[m][n] = mfma16(af[m][ks], bfr[n][ks], acc[m][n]);

    __syncthreads();   // drains vmcnt (stage done) + all waves done reading buf
  }

  if constexpr (MODE == 0){
    u16* Dh = wc ? O1h : O0h;
    u16* Dl = wc ? O1l : O0l;
    const size_t base = (size_t)bc*BN*DD;        // head = bc
    #pragma unroll
    for (int m=0;m<4;++m)
      #pragma unroll
      for (int n=0;n<4;++n)
        #pragma unroll
        for (int j=0;j<4;++j){
          int r = row0 + wr*64 + m*16 + lg*4 + j;
          int d = n*16 + lr;
          size_t o = base + (size_t)r*DD + d;
          u16 hi, lo; split2(acc[m][n][j], hi, lo);
          Dh[o] = hi; Dl[o] = lo;
        }
  } else {
    #pragma unroll
    for (int m=0;m<4;++m)
      #pragma unroll
      for (int n=0;n<4;++n){
        int c = col0 + wc*64 + n*16 + lr;
        int hh = c >> 6, d = c & 63;
        int r = row0 + wr*64 + m*16 + lg*4;
        int b = r >> 10, nn = r & 1023;
        ushort4 pk;
        pk.x = f2bf(acc[m][n][0]); pk.y = f2bf(acc[m][n][1]);
        pk.z = f2bf(acc[m][n][2]); pk.w = f2bf(acc[m][n][3]);
        *(ushort4*)(O0h + ((size_t)((hh*16 + b)*DD + d))*NN + nn) = pk;
      }
  }
}

// ---------------- flash attention v4: score double-buffer pipeline ----------------
// Swapped operands (lane owns q-col). Per body(t): QK(t+1) MFMAs (from LDS K dbuf) are
// independent of softmax(t) VALU -> compiler interleaves; PV(t) closes. Barrier at body
// top drains stage(t+1); stage(t+2) issued mid-body. ls kept per-lane (reduced once at
// epilogue). Defer-max THR=8 (exact: P,ls,acc all share the same deferred scale).
__global__ __launch_bounds__(256) void flash_k(const u16* __restrict__ Qh, const u16* __restrict__ Ql,
                                               const u16* __restrict__ Kh, const u16* __restrict__ Kl,
                                               const u16* __restrict__ Vt, u16* __restrict__ Cc){
  __shared__ u16 kbuf[2][2][4096];                 // [buf][hi/lo][64*64] = 32 KB
  const int flat = blockIdx.x;
  const int swz = (flat & 7)*192 + (flat >> 3);    // XCD chunking: K/V of a (b,h) stay in one L2
  const int qb = swz & 7, h = (swz >> 3) % 12, b = swz / 96;
  const int l = threadIdx.x & 63, w = threadIdx.x >> 6, lr = l & 15, lg = l >> 4;
  const size_t hb = (size_t)h*BN*DD + (size_t)b*NN*DD;
  const size_t vtb = (size_t)((h*16 + b)*DD);
  const int q0 = qb*128 + w*32;

  // staging geometry: chunk = 8 rows x 128B; lane l covers row (l>>3), swizzled col 8*((l&7)^(l>>3))
  const int srow = l >> 3;
  const int scol = 8*((l & 7) ^ srow);

  auto stage = [&](int buf, int t){
    const int kv0 = t*64;
    #pragma unroll
    for (int j=0;j<4;++j){
      const int c = w*4 + j;                       // 0..15: 0-7 Kh, 8-15 Kl
      const u16* src = (c < 8) ? Kh : Kl;
      const int cr = (c & 7)*8;
      stage16(src + hb + (size_t)(kv0 + cr + srow)*DD + scol,
              &kbuf[buf][c >> 3][(c & 7)*512]);
    }
  };

  // hoist Q B-frags (col = lr -> q, k = lg*8 contiguous along D)
  bf16x8 qfh[2][2], qfl[2][2];
  #pragma unroll
  for (int qf=0;qf<2;++qf)
    #pragma unroll
    for (int ks=0;ks<2;++ks){
      size_t o = hb + (size_t)(q0 + qf*16 + lr)*DD + ks*32 + lg*8;
      qfh[qf][ks] = ld8(Qh + o);
      qfl[qf][ks] = ld8(Ql + o);
    }

  f32x4 acc[2][4];                 // [qf][df] : O^T frags (row=d, col=q)
  float mr[2] = {-1e30f,-1e30f}, ls[2] = {0.f,0.f};   // ls per-lane partial
  #pragma unroll
  for (int qf=0;qf<2;++qf)
    #pragma unroll
    for (int df=0;df<4;++df) acc[qf][df] = f32x4{0.f,0.f,0.f,0.f};

  f32x4 sA[2][4], sB[2][4];

  // QK(t) from kbuf[bufc] -> sN
  auto qk = [&](f32x4 (&sN)[2][4], int bufc){
    #pragma unroll
    for (int qf=0;qf<2;++qf)
      #pragma unroll
      for (int kf=0;kf<4;++kf) sN[qf][kf] = f32x4{0.f,0.f,0.f,0.f};
    const char* kb = (const char*)&kbuf[bufc][0][0];
    #pragma unroll
    for (int ks=0;ks<2;++ks){
      bf16x8 kh[4], kl2[4];
      #pragma unroll
      for (int kf=0;kf<4;++kf){
        const int r = kf*16 + lr;
        const int sw = (ks*64 + lg*16) ^ ((lr & 7) << 4);
        kh[kf]  = *(const bf16x8*)(kb + r*128 + sw);
        kl2[kf] = *(const bf16x8*)(kb + 8192 + r*128 + sw);
      }
      __builtin_amdgcn_s_setprio(1);
      #pragma unroll
      for (int qf=0;qf<2;++qf)
        #pragma unroll
        for (int kf=0;kf<4;++kf){
          sN[qf][kf] = mfma16(kh[kf],  qfh[qf][ks], sN[qf][kf]);
          sN[qf][kf] = mfma16(kl2[kf], qfh[qf][ks], sN[qf][kf]);
          sN[qf][kf] = mfma16(kh[kf],  qfl[qf][ks], sN[qf][kf]);
        }
      __builtin_amdgcn_s_setprio(0);
    }
  };

  // body(t): softmax+PV on sCur; QK(t+1)->sNxt from kbuf[cur^1]; stage(t+2)->kbuf[cur]
  auto body = [&](int t, f32x4 (&sCur)[2][4], f32x4 (&sNxt)[2][4], int cur){
    __syncthreads();                               // stage(t+1) done; kbuf[cur] free

    if (t + 1 < 16) qk(sNxt, cur ^ 1);             // MFMA pipe (overlaps softmax below)
    if (t + 2 < 16) stage(cur, t + 2);

    // V^T A-frags for PV(t), permuted addressing (k (lg,j) -> kv = 32ks+16(j>>2)+4lg+(j&3))
    const int kv0 = t*64;
    bf16x8 va[4][2];
    #pragma unroll
    for (int df=0;df<4;++df)
      #pragma unroll
      for (int ks=0;ks<2;++ks){
        const u16* vp = Vt + (vtb + df*16 + lr)*NN + kv0 + ks*32 + lg*4;
        U8 vu;
        vu.q[0] = *(const ushort4*)(vp);
        vu.q[1] = *(const ushort4*)(vp + 16);
        va[df][ks] = vu.v;
      }

    // softmax on sCur (exp2 domain; per lane: 2 q-rows; defer-max THR=8)
    bf16x8 pb[2][2];
    #pragma unroll
    for (int qf=0;qf<2;++qf){
      float a0 = fmaxf(fmaxf(sCur[qf][0][0], sCur[qf][0][1]), sCur[qf][0][2]);
      float a1 = fmaxf(fmaxf(sCur[qf][0][3], sCur[qf][1][0]), sCur[qf][1][1]);
      float a2 = fmaxf(fmaxf(sCur[qf][1][2], sCur[qf][1][3]), sCur[qf][2][0]);
      float a3 = fmaxf(fmaxf(sCur[qf][2][1], sCur[qf][2][2]), sCur[qf][2][3]);
      float a4 = fmaxf(fmaxf(sCur[qf][3][0], sCur[qf][3][1]), sCur[qf][3][2]);
      float pm = fmaxf(fmaxf(fmaxf(a0, a1), a2), fmaxf(fmaxf(a3, a4), sCur[qf][3][3]));
      pm = fmaxf(pm, __shfl_xor(pm, 16, 64));
      pm = fmaxf(pm, __shfl_xor(pm, 32, 64));
      if (!__all(pm <= mr[qf] + 8.f)){             // rescale only on big max growth
        const float mn = fmaxf(mr[qf], pm);
        const float fs = exp2f(mr[qf] - mn);
        mr[qf] = mn;
        ls[qf] *= fs;
        #pragma unroll
        for (int df=0;df<4;++df)
          #pragma unroll
          for (int r=0;r<4;++r) acc[qf][df][r] *= fs;
      }
      float rs = 0.f;
      #pragma unroll
      for (int kf=0;kf<4;++kf)
        #pragma unroll
        for (int r=0;r<4;++r){
          float e = exp2f(sCur[qf][kf][r] - mr[qf]);
          sCur[qf][kf][r] = e;
          rs += e;
        }
      ls[qf] += rs;                                // per-lane partial; reduced at epilogue
      // pack P as PV B-frag, k-permuted: elem j <- sCur[qf][2ks + (j>>2)][j&3]
      #pragma unroll
      for (int ks=0;ks<2;++ks){
        U8 pu;
        #pragma unroll
        for (int j=0;j<8;++j) pu.e[j] = f2bf(sCur[qf][2*ks + (j>>2)][j&3]);
        pb[qf][ks] = pu.v;
      }
    }

    // PV: O^T += V^T * P
    __builtin_amdgcn_s_setprio(1);
    #pragma unroll
    for (int ks=0;ks<2;++ks)
      #pragma unroll
      for (int qf=0;qf<2;++qf)
        #pragma unroll
        for (int df=0;df<4;++df)
          acc[qf][df] = mfma16(va[df][ks], pb[qf][ks], acc[qf][df]);
    __builtin_amdgcn_s_setprio(0);
  };

  // prologue
  stage(0, 0);
  __syncthreads();                                 // K(0) ready
  qk(sA, 0);                                       // scores(0)
  stage(1, 1);                                     // K(1) -> kbuf[1]

  for (int tt=0; tt<8; ++tt){
    body(tt*2,     sA, sB, 0);                     // consumes sA(t even), builds sB(t+1)
    body(tt*2 + 1, sB, sA, 1);                     // consumes sB(t odd),  builds sA(t+1)
  }

  // epilogue: reduce ls across the 4 lane-groups, normalize, write concat
  #pragma unroll
  for (int qf=0;qf<2;++qf){
    float t1 = ls[qf] + __shfl_xor(ls[qf], 16, 64);
    t1 += __shfl_xor(t1, 32, 64);
    const float inv = 1.0f / t1;
    #pragma unroll
    for (int df=0;df<4;++df){
      ushort4 o4;
      o4.x = f2bf(acc[qf][df][0]*inv);
      o4.y = f2bf(acc[qf][df][1]*inv);
      o4.z = f2bf(acc[qf][df][2]*inv);
      o4.w = f2bf(acc[qf][df][3]*inv);
      *(ushort4*)(Cc + (size_t)(b*NN + q0 + qf*16 + lr)*EE + h*DD + df*16 + lg*4) = o4;
    }
  }
}

// ---------------- output projection ----------------
__global__ __launch_bounds__(256) void gemm_o_k(const u16* __restrict__ Cc, const u16* __restrict__ Wot,
                                                float* __restrict__ out){
  const int rt = blockIdx.x;
  const int w = threadIdx.x >> 6, l = threadIdx.x & 63, lr = l & 15, lg = l >> 4;
  const int row0 = rt*64 + w*16;
  f32x4 acc[4];
  #pragma unroll
  for (int n=0;n<4;++n) acc[n] = f32x4{0.f,0.f,0.f,0.f};

  for (int kt=0; kt<12; ++kt){
    const int e0 = kt*64;
    bf16x8 a[2], bb[4][2];
    #pragma unroll
    for (int ks=0;ks<2;++ks)
      a[ks] = ld8(Cc + (size_t)(row0 + lr)*EE + e0 + ks*32 + lg*8);
    #pragma unroll
    for (int nf=0;nf<4;++nf)
      #pragma unroll
      for (int ks=0;ks<2;++ks)
        bb[nf][ks] = ld8(Wot + (size_t)(nf*16 + lr)*EE + e0 + ks*32 + lg*8);
    #pragma unroll
    for (int ks=0;ks<2;++ks)
      #pragma unroll
      for (int nf=0;nf<4;++nf)
        acc[nf] = mfma16(a[ks], bb[nf][ks], acc[nf]);
  }
  #pragma unroll
  for (int nf=0;nf<4;++nf)
    #pragma unroll
    for (int j=0;j<4;++j)
      out[(size_t)(row0 + lg*4 + j)*DD + nf*16 + lr] = acc[nf][j];
}

// ---------------- launch ----------------
extern "C" void kernel_launch(void* const* d_in, const int* in_sizes, int n_in,
                              void* d_out, int out_size, void* d_ws, size_t ws_size,
                              hipStream_t stream) {
  const float* x  = (const float*)d_in[0];
  const float* Wq = (const float*)d_in[1];
  const float* Wk = (const float*)d_in[2];
  const float* Wv = (const float*)d_in[3];
  const float* Wo = (const float*)d_in[4];
  float* out = (float*)d_out;

  u16* ws = (u16*)d_ws;
  const size_t SB = (size_t)12582912;   // 16384*768
  u16* Xh  = ws;
  u16* Xl  = Xh + SB;
  u16* Qh  = Xl + SB;
  u16* Ql  = Qh + SB;
  u16* Kh  = Ql + SB;
  u16* Kl  = Kh + SB;
  u16* Vt  = Kl + SB;
  u16* Cc  = Vt + SB;
  u16* Wot = Cc + SB;
  // BT1/BT2 alias into Cc: written by packs, read by GEMMs, then Cc is fully
  // overwritten by flash_k before gemm_o_k reads it (in-stream ordering).
  u16* BT1 = Cc;                        // 1536*2304 = 3538944 elems
  u16* BT2 = Cc + 3538944;              // 768*768   =  589824 elems

  split_x_k <<<12288, 256, 0, stream>>>(x, Xh, Xl);
  pack_bt1_k<<<13824, 256, 0, stream>>>(Wq, Wk, BT1);
  pack_bt2_k<<<2304,  256, 0, stream>>>(Wv, BT2);
  pack_wo_k <<<192,   256, 0, stream>>>(Wo, Wot);

  gemm_big_k<36,0><<<1536, 256, 0, stream>>>(Xh, Xl, BT1, Qh, Ql, Kh, Kl);
  gemm_big_k<12,1><<<768,  256, 0, stream>>>(Xh, Xl, BT2, Vt, nullptr, nullptr, nullptr);
  flash_k   <<<1536, 256, 0, stream>>>(Qh, Ql, Kh, Kl, Vt, Cc);
  gemm_o_k  <<<256,  256, 0, stream>>>(Cc, Wot, out);
}

// Round 6
// 435.668 us; speedup vs baseline: 1.1573x; 1.1573x over previous
//
#include <hip/hip_runtime.h>
#include <hip/hip_bf16.h>

typedef unsigned short u16;
typedef unsigned int u32;
typedef __attribute__((ext_vector_type(8))) short bf16x8;   // 8 bf16 in 4 VGPRs
typedef __attribute__((ext_vector_type(4))) float f32x4;

#define DEV static __device__ __forceinline__

#define BB 16
#define NN 1024
#define EE 768
#define HH 12
#define DD 64
#define BN (BB*NN)   // 16384

DEV u16 f2bf(float f){ __hip_bfloat16 h = __float2bfloat16(f); u16 u; __builtin_memcpy(&u, &h, 2); return u; }
DEV float bf2f(u16 u){ __hip_bfloat16 h; __builtin_memcpy(&h, &u, 2); return __bfloat162float(h); }
DEV void split2(float v, u16& hi, u16& lo){ hi = f2bf(v); lo = f2bf(v - bf2f(hi)); }
DEV bf16x8 ld8(const u16* p){ return *(const bf16x8*)p; }
DEV f32x4 mfma16(bf16x8 a, bf16x8 b, f32x4 c){ return __builtin_amdgcn_mfma_f32_16x16x32_bf16(a, b, c, 0, 0, 0); }
DEV u32 pk2(float a, float b){                       // 2xf32 -> packed 2xbf16 (v_cvt_pk_bf16_f32)
  float2 f{a, b};
  __hip_bfloat162 t = __float22bfloat162_rn(f);
  u32 r; __builtin_memcpy(&r, &t, 4); return r;
}

union U8 { bf16x8 v; u16 e[8]; ushort4 q[2]; u32 w[4]; };

// async global->LDS, 16B per lane. LDS dst must be wave-uniform; HW adds lane*16.
DEV void stage16(const u16* g, u16* l){
  __builtin_amdgcn_global_load_lds((const __attribute__((address_space(1))) void*)g,
                                   (__attribute__((address_space(3))) void*)l,
                                   16, 0, 0);
}

// ---------------- prep kernels ----------------

__global__ __launch_bounds__(256) void split_x_k(const float* __restrict__ x,
                                                 u16* __restrict__ xh, u16* __restrict__ xl){
  int i = blockIdx.x*256 + threadIdx.x;          // < 3145728
  const float4 v = ((const float4*)x)[i];
  ushort4 h, l;
  split2(v.x, h.x, l.x);
  split2(v.y, h.y, l.y);
  split2(v.z, h.z, l.z);
  split2(v.w, h.w, l.w);
  ((ushort4*)xh)[i] = h;
  ((ushort4*)xl)[i] = l;
}

// BT1[1536][2304]: col c -> head h=c>>7, group g=(c>>6)&1 (0=Q,1=K), d=c&63.
// k: seg 0 = W_hi, seg 1 = W_lo, seg 2 = W_hi  (pairs with A_ext = [Xh|Xh|Xl]).
// Q scale folds 1/sqrt(D) AND log2(e): flash softmax runs in exp2 domain.
__global__ __launch_bounds__(256) void pack_bt1_k(const float* __restrict__ Wq,
                                                  const float* __restrict__ Wk,
                                                  u16* __restrict__ BT1){
  int i = blockIdx.x*256 + threadIdx.x;          // < 3538944
  int c = i / 2304, k = i - c*2304;
  int seg = (k >= 768) + (k >= 1536);
  int e = k - seg*768;
  int h = c >> 7, g = (c >> 6) & 1, d = c & 63;
  const float* W = g ? Wk : Wq;
  float v = W[((size_t)h*EE + e)*DD + d] * (g ? 1.0f : 0.125f*1.4426950408889634f);
  u16 hi, lo; split2(v, hi, lo);
  BT1[i] = (seg == 1) ? lo : hi;
}

// BT2[768][768]: col c -> h=c>>6, d=c&63; k=e. Plain bf16.
__global__ __launch_bounds__(256) void pack_bt2_k(const float* __restrict__ Wv,
                                                  u16* __restrict__ BT2){
  int i = blockIdx.x*256 + threadIdx.x;          // < 589824
  int c = i / 768, e = i - c*768;
  int h = c >> 6, d = c & 63;
  BT2[i] = f2bf(Wv[((size_t)h*EE + e)*DD + d]);
}

__global__ __launch_bounds__(256) void pack_wo_k(const float* __restrict__ W, u16* __restrict__ Wt){
  int i = blockIdx.x*256 + threadIdx.x;          // < 49152
  int j = i & 63, k = i >> 6;
  Wt[(size_t)j*EE + k] = f2bf(W[i]);
}

// ---------------- big staged GEMM (m97-style 2-phase, 128x128 tile, BK=64) ----------------
template<int KT, int MODE>
__global__ __launch_bounds__(256) void gemm_big_k(const u16* __restrict__ Xh, const u16* __restrict__ Xl,
                                                  const u16* __restrict__ BT,
                                                  u16* __restrict__ O0h, u16* __restrict__ O0l,
                                                  u16* __restrict__ O1h, u16* __restrict__ O1l){
  __shared__ u16 lds[2][2][8192];                // [buf][A/B][128*64] = 64 KB
  constexpr int NB  = (MODE == 0) ? 12 : 6;      // col-tiles
  constexpr int CPX = (MODE == 0) ? 192 : 96;    // blocks per XCD chunk
  constexpr int KE  = KT*64;                     // B K-extent (elems)

  const int flat = blockIdx.x;
  const int swz = (flat & 7)*CPX + (flat >> 3);  // XCD-chunked, bc fastest (A-panel L2 reuse)
  const int rt = swz / NB, bc = swz - rt*NB;
  const int row0 = rt*128, col0 = bc*128;
  const int tid = threadIdx.x;
  const int w = tid >> 6, l = tid & 63, lr = l & 15, lg = l >> 4;
  const int wr = w >> 1, wc = w & 1;
  const int sr = l >> 3, sce = (l & 7)*8;        // staging: row-in-8, col elem

  f32x4 acc[4][4];
  #pragma unroll
  for (int m=0;m<4;++m)
    #pragma unroll
    for (int n=0;n<4;++n) acc[m][n] = f32x4{0.f,0.f,0.f,0.f};

  auto stage = [&](int buf, int kt){
    const u16* asrc = (MODE == 0 && kt >= 24) ? Xl : Xh;
    const int e0 = (MODE == 0) ? (kt - (kt >= 24 ? 24 : (kt >= 12 ? 12 : 0)))*64 : kt*64;
    const u16* ab = asrc + (size_t)row0*EE + e0 + sce;
    const u16* bb = BT + (size_t)col0*KE + kt*64 + sce;
    u16* la = &lds[buf][0][0];
    u16* lb = &lds[buf][1][0];
    #pragma unroll
    for (int j=0;j<4;++j){
      const int it = j*4 + w;                    // 16 sub-blocks of 8 rows
      stage16(ab + (size_t)(it*8 + sr)*EE, la + it*512);
      stage16(bb + (size_t)(it*8 + sr)*KE, lb + it*512);
    }
  };

  stage(0, 0);
  __syncthreads();

  for (int kt=0; kt<KT; ++kt){
    const int buf = kt & 1;
    if (kt + 1 < KT) stage(buf ^ 1, kt + 1);

    const u16* la = &lds[buf][0][0];
    const u16* lb = &lds[buf][1][0];
    bf16x8 af[4][2], bfr[4][2];
    #pragma unroll
    for (int m=0;m<4;++m)
      #pragma unroll
      for (int ks=0;ks<2;++ks)
        af[m][ks] = ld8(la + (wr*64 + m*16 + lr)*64 + ks*32 + lg*8);
    #pragma unroll
    for (int n=0;n<4;++n)
      #pragma unroll
      for (int ks=0;ks<2;++ks)
        bfr[n][ks] = ld8(lb + (wc*64 + n*16 + lr)*64 + ks*32 + lg*8);

    #pragma unroll
    for (int ks=0;ks<2;++ks)
      #pragma unroll
      for (int m=0;m<4;++m)
        #pragma unroll
        for (int n=0;n<4;++n)
          acc[m][n] = mfma16(af[m][ks], bfr[n][ks], acc[m][n]);

    __syncthreads();   // drains vmcnt (stage done) + all waves done reading buf
  }

  if constexpr (MODE == 0){
    u16* Dh = wc ? O1h : O0h;
    u16* Dl = wc ? O1l : O0l;
    const size_t base = (size_t)bc*BN*DD;        // head = bc
    #pragma unroll
    for (int m=0;m<4;++m)
      #pragma unroll
      for (int n=0;n<4;++n)
        #pragma unroll
        for (int j=0;j<4;++j){
          int r = row0 + wr*64 + m*16 + lg*4 + j;
          int d = n*16 + lr;
          size_t o = base + (size_t)r*DD + d;
          u16 hi, lo; split2(acc[m][n][j], hi, lo);
          Dh[o] = hi; Dl[o] = lo;
        }
  } else {
    #pragma unroll
    for (int m=0;m<4;++m)
      #pragma unroll
      for (int n=0;n<4;++n){
        int c = col0 + wc*64 + n*16 + lr;
        int hh = c >> 6, d = c & 63;
        int r = row0 + wr*64 + m*16 + lg*4;
        int b = r >> 10, nn = r & 1023;
        ushort4 pk;
        pk.x = f2bf(acc[m][n][0]); pk.y = f2bf(acc[m][n][1]);
        pk.z = f2bf(acc[m][n][2]); pk.w = f2bf(acc[m][n][3]);
        *(ushort4*)(O0h + ((size_t)((hh*16 + b)*DD + d))*NN + nn) = pk;
      }
  }
}

// ---------------- flash attention v5: r3 structure + lazy group rescale ----------------
// K hi/lo staged via global_load_lds (pre-swizzled source, XOR-swizzled b128 reads).
// Softmax exp2-domain. Lazy rescale: group-uniform mr; common path does NO cross-lane
// shuffles (per-lane local max + wave-uniform __any trigger); P bounded by 2^8 (exact).
// ls kept as per-lane partial, reduced once at epilogue.
__global__ __launch_bounds__(256) void flash_k(const u16* __restrict__ Qh, const u16* __restrict__ Ql,
                                               const u16* __restrict__ Kh, const u16* __restrict__ Kl,
                                               const u16* __restrict__ Vt, u16* __restrict__ Cc){
  __shared__ u16 kbuf[2][2][4096];                 // [buf][hi/lo][64*64] = 32 KB
  const int flat = blockIdx.x;
  const int swz = (flat & 7)*192 + (flat >> 3);    // XCD chunking: K/V of a (b,h) stay in one L2
  const int qb = swz & 7, h = (swz >> 3) % 12, b = swz / 96;
  const int l = threadIdx.x & 63, w = threadIdx.x >> 6, lr = l & 15, lg = l >> 4;
  const size_t hb = (size_t)h*BN*DD + (size_t)b*NN*DD;
  const size_t vtb = (size_t)((h*16 + b)*DD);
  const int q0 = qb*128 + w*32;

  // staging geometry: chunk = 8 rows x 128B; lane l covers row (l>>3), swizzled col 8*((l&7)^(l>>3))
  const int srow = l >> 3;
  const int scol = 8*((l & 7) ^ srow);

  auto stage = [&](int buf, int t){
    const int kv0 = t*64;
    #pragma unroll
    for (int j=0;j<4;++j){
      const int c = w*4 + j;                       // 0..15: 0-7 Kh, 8-15 Kl
      const u16* src = (c < 8) ? Kh : Kl;
      const int cr = (c & 7)*8;
      stage16(src + hb + (size_t)(kv0 + cr + srow)*DD + scol,
              &kbuf[buf][c >> 3][(c & 7)*512]);
    }
  };

  // hoist Q B-frags (col = lr -> q, k = lg*8 contiguous along D)
  bf16x8 qfh[2][2], qfl[2][2];
  #pragma unroll
  for (int qf=0;qf<2;++qf)
    #pragma unroll
    for (int ks=0;ks<2;++ks){
      size_t o = hb + (size_t)(q0 + qf*16 + lr)*DD + ks*32 + lg*8;
      qfh[qf][ks] = ld8(Qh + o);
      qfl[qf][ks] = ld8(Ql + o);
    }

  f32x4 acc[2][4];                 // [qf][df] : O^T frags (row=d, col=q)
  float mr[2] = {-1e30f,-1e30f}, ls[2] = {0.f,0.f};   // ls = per-lane partial
  #pragma unroll
  for (int qf=0;qf<2;++qf)
    #pragma unroll
    for (int df=0;df<4;++df) acc[qf][df] = f32x4{0.f,0.f,0.f,0.f};

  stage(0, 0);
  __syncthreads();

  for (int t=0;t<16;++t){
    const int buf = t & 1;
    const int kv0 = t*64;

    // V^T A-frags first (oldest vmem ops -> waiting for them leaves stage in flight)
    bf16x8 va[4][2];
    #pragma unroll
    for (int df=0;df<4;++df)
      #pragma unroll
      for (int ks=0;ks<2;++ks){
        const u16* vp = Vt + (vtb + df*16 + lr)*NN + kv0 + ks*32 + lg*4;
        U8 vu;
        vu.q[0] = *(const ushort4*)(vp);
        vu.q[1] = *(const ushort4*)(vp + 16);
        va[df][ks] = vu.v;
      }

    if (t + 1 < 16) stage(buf ^ 1, t + 1);         // prefetch next K tile (hides under softmax+PV)

    // QK^T from LDS (swapped, 3-pass), per-ks frag window
    f32x4 s[2][4];                 // [qf][kf]
    #pragma unroll
    for (int qf=0;qf<2;++qf)
      #pragma unroll
      for (int kf=0;kf<4;++kf) s[qf][kf] = f32x4{0.f,0.f,0.f,0.f};

    const char* kb = (const char*)&kbuf[buf][0][0];
    #pragma unroll
    for (int ks=0;ks<2;++ks){
      bf16x8 kh[4], kl2[4];
      #pragma unroll
      for (int kf=0;kf<4;++kf){
        const int r = kf*16 + lr;
        const int sw = (ks*64 + lg*16) ^ ((lr & 7) << 4);
        kh[kf]  = *(const bf16x8*)(kb + r*128 + sw);
        kl2[kf] = *(const bf16x8*)(kb + 8192 + r*128 + sw);
      }
      __builtin_amdgcn_s_setprio(1);
      #pragma unroll
      for (int qf=0;qf<2;++qf)
        #pragma unroll
        for (int kf=0;kf<4;++kf){
          s[qf][kf] = mfma16(kh[kf],  qfh[qf][ks], s[qf][kf]);
          s[qf][kf] = mfma16(kl2[kf], qfh[qf][ks], s[qf][kf]);
          s[qf][kf] = mfma16(kh[kf],  qfl[qf][ks], s[qf][kf]);
        }
      __builtin_amdgcn_s_setprio(0);
    }

    // softmax (exp2 domain; lazy group rescale; per lane: 2 q-rows)
    bf16x8 pb[2][2];
    #pragma unroll
    for (int qf=0;qf<2;++qf){
      // lane-local max of this lane's 16 scores
      float a0 = fmaxf(fmaxf(s[qf][0][0], s[qf][0][1]), fmaxf(s[qf][0][2], s[qf][0][3]));
      float a1 = fmaxf(fmaxf(s[qf][1][0], s[qf][1][1]), fmaxf(s[qf][1][2], s[qf][1][3]));
      float a2 = fmaxf(fmaxf(s[qf][2][0], s[qf][2][1]), fmaxf(s[qf][2][2], s[qf][2][3]));
      float a3 = fmaxf(fmaxf(s[qf][3][0], s[qf][3][1]), fmaxf(s[qf][3][2], s[qf][3][3]));
      float pm = fmaxf(fmaxf(a0, a1), fmaxf(a2, a3));
      if (__any(pm > mr[qf] + 8.f)){               // rare: true max growth -> full rescale
        pm = fmaxf(pm, __shfl_xor(pm, 16, 64));    // group max (4 lanes share a q-column)
        pm = fmaxf(pm, __shfl_xor(pm, 32, 64));
        const float mn = fmaxf(mr[qf], pm);
        const float fs = exp2f(mr[qf] - mn);
        mr[qf] = mn;
        ls[qf] *= fs;
        #pragma unroll
        for (int df=0;df<4;++df)
          #pragma unroll
          for (int r=0;r<4;++r) acc[qf][df][r] *= fs;
      }
      float rs = 0.f;
      #pragma unroll
      for (int kf=0;kf<4;++kf)
        #pragma unroll
        for (int r=0;r<4;++r){
          float e = exp2f(s[qf][kf][r] - mr[qf]);  // bounded by 2^8
          s[qf][kf][r] = e;
          rs += e;
        }
      ls[qf] += rs;                                // per-lane partial
      // pack P as PV B-frag, k-permuted: elem j <- s[qf][2ks + (j>>2)][j&3]
      #pragma unroll
      for (int ks=0;ks<2;++ks){
        U8 pu;
        pu.w[0] = pk2(s[qf][2*ks][0],   s[qf][2*ks][1]);
        pu.w[1] = pk2(s[qf][2*ks][2],   s[qf][2*ks][3]);
        pu.w[2] = pk2(s[qf][2*ks+1][0], s[qf][2*ks+1][1]);
        pu.w[3] = pk2(s[qf][2*ks+1][2], s[qf][2*ks+1][3]);
        pb[qf][ks] = pu.v;
      }
    }

    // PV: O^T += V^T * P
    __builtin_amdgcn_s_setprio(1);
    #pragma unroll
    for (int ks=0;ks<2;++ks)
      #pragma unroll
      for (int qf=0;qf<2;++qf)
        #pragma unroll
        for (int df=0;df<4;++df)
          acc[qf][df] = mfma16(va[df][ks], pb[qf][ks], acc[qf][df]);
    __builtin_amdgcn_s_setprio(0);

    __syncthreads();               // stage(t+1) drained; all waves done with kbuf[buf]
  }

  // epilogue: reduce ls across the 4 lane-groups, normalize, write concat
  #pragma unroll
  for (int qf=0;qf<2;++qf){
    float t1 = ls[qf] + __shfl_xor(ls[qf], 16, 64);
    t1 += __shfl_xor(t1, 32, 64);
    const float inv = 1.0f / t1;
    #pragma unroll
    for (int df=0;df<4;++df){
      ushort4 o4;
      o4.x = f2bf(acc[qf][df][0]*inv);
      o4.y = f2bf(acc[qf][df][1]*inv);
      o4.z = f2bf(acc[qf][df][2]*inv);
      o4.w = f2bf(acc[qf][df][3]*inv);
      *(ushort4*)(Cc + (size_t)(b*NN + q0 + qf*16 + lr)*EE + h*DD + df*16 + lg*4) = o4;
    }
  }
}

// ---------------- output projection ----------------
__global__ __launch_bounds__(256) void gemm_o_k(const u16* __restrict__ Cc, const u16* __restrict__ Wot,
                                                float* __restrict__ out){
  const int rt = blockIdx.x;
  const int w = threadIdx.x >> 6, l = threadIdx.x & 63, lr = l & 15, lg = l >> 4;
  const int row0 = rt*64 + w*16;
  f32x4 acc[4];
  #pragma unroll
  for (int n=0;n<4;++n) acc[n] = f32x4{0.f,0.f,0.f,0.f};

  for (int kt=0; kt<12; ++kt){
    const int e0 = kt*64;
    bf16x8 a[2], bb[4][2];
    #pragma unroll
    for (int ks=0;ks<2;++ks)
      a[ks] = ld8(Cc + (size_t)(row0 + lr)*EE + e0 + ks*32 + lg*8);
    #pragma unroll
    for (int nf=0;nf<4;++nf)
      #pragma unroll
      for (int ks=0;ks<2;++ks)
        bb[nf][ks] = ld8(Wot + (size_t)(nf*16 + lr)*EE + e0 + ks*32 + lg*8);
    #pragma unroll
    for (int ks=0;ks<2;++ks)
      #pragma unroll
      for (int nf=0;nf<4;++nf)
        acc[nf] = mfma16(a[ks], bb[nf][ks], acc[nf]);
  }
  #pragma unroll
  for (int nf=0;nf<4;++nf)
    #pragma unroll
    for (int j=0;j<4;++j)
      out[(size_t)(row0 + lg*4 + j)*DD + nf*16 + lr] = acc[nf][j];
}

// ---------------- launch ----------------
extern "C" void kernel_launch(void* const* d_in, const int* in_sizes, int n_in,
                              void* d_out, int out_size, void* d_ws, size_t ws_size,
                              hipStream_t stream) {
  const float* x  = (const float*)d_in[0];
  const float* Wq = (const float*)d_in[1];
  const float* Wk = (const float*)d_in[2];
  const float* Wv = (const float*)d_in[3];
  const float* Wo = (const float*)d_in[4];
  float* out = (float*)d_out;

  u16* ws = (u16*)d_ws;
  const size_t SB = (size_t)12582912;   // 16384*768
  u16* Xh  = ws;
  u16* Xl  = Xh + SB;
  u16* Qh  = Xl + SB;
  u16* Ql  = Qh + SB;
  u16* Kh  = Ql + SB;
  u16* Kl  = Kh + SB;
  u16* Vt  = Kl + SB;
  u16* Cc  = Vt + SB;
  u16* Wot = Cc + SB;
  // BT1/BT2 alias into Cc: written by packs, read by GEMMs, then Cc is fully
  // overwritten by flash_k before gemm_o_k reads it (in-stream ordering).
  u16* BT1 = Cc;                        // 1536*2304 = 3538944 elems
  u16* BT2 = Cc + 3538944;              // 768*768   =  589824 elems

  split_x_k <<<12288, 256, 0, stream>>>(x, Xh, Xl);
  pack_bt1_k<<<13824, 256, 0, stream>>>(Wq, Wk, BT1);
  pack_bt2_k<<<2304,  256, 0, stream>>>(Wv, BT2);
  pack_wo_k <<<192,   256, 0, stream>>>(Wo, Wot);

  gemm_big_k<36,0><<<1536, 256, 0, stream>>>(Xh, Xl, BT1, Qh, Ql, Kh, Kl);
  gemm_big_k<12,1><<<768,  256, 0, stream>>>(Xh, Xl, BT2, Vt, nullptr, nullptr, nullptr);
  flash_k   <<<1536, 256, 0, stream>>>(Qh, Ql, Kh, Kl, Vt, Cc);
  gemm_o_k  <<<256,  256, 0, stream>>>(Cc, Wot, out);
}

// Round 8
// 379.031 us; speedup vs baseline: 1.3303x; 1.1494x over previous
//
#include <hip/hip_runtime.h>
#include <hip/hip_bf16.h>

typedef unsigned short u16;
typedef unsigned int u32;
typedef __attribute__((ext_vector_type(8))) short bf16x8;   // 8x16-bit in 4 VGPRs
typedef __attribute__((ext_vector_type(4))) float f32x4;

#define DEV static __device__ __forceinline__

#define BB 16
#define NN 1024
#define EE 768
#define HH 12
#define DD 64
#define BN (BB*NN)   // 16384

DEV u16 f2bf(float f){ __hip_bfloat16 h = __float2bfloat16(f); u16 u; __builtin_memcpy(&u, &h, 2); return u; }
DEV float bf2f(u16 u){ __hip_bfloat16 h; __builtin_memcpy(&h, &u, 2); return __bfloat162float(h); }
DEV void split2(float v, u16& hi, u16& lo){ hi = f2bf(v); lo = f2bf(v - bf2f(hi)); }
DEV bf16x8 ld8(const u16* p){ return *(const bf16x8*)p; }
DEV f32x4 mfma16(bf16x8 a, bf16x8 b, f32x4 c){ return __builtin_amdgcn_mfma_f32_16x16x32_bf16(a, b, c, 0, 0, 0); }
DEV u32 pk2(float a, float b){                       // 2xf32 -> packed 2xbf16 (v_cvt_pk_bf16_f32)
  float2 f{a, b};
  __hip_bfloat162 t = __float22bfloat162_rn(f);
  u32 r; __builtin_memcpy(&r, &t, 4); return r;
}

union U8 { bf16x8 v; u16 e[8]; ushort4 q[2]; u32 w[4]; };

// async global->LDS, 16B per lane. LDS dst must be wave-uniform; HW adds lane*16.
DEV void stage16(const u16* g, u16* l){
  __builtin_amdgcn_global_load_lds((const __attribute__((address_space(1))) void*)g,
                                   (__attribute__((address_space(3))) void*)l,
                                   16, 0, 0);
}

// ---------------- prep kernels ----------------

__global__ __launch_bounds__(256) void split_x_k(const float* __restrict__ x,
                                                 u16* __restrict__ xh, u16* __restrict__ xl){
  int i = blockIdx.x*256 + threadIdx.x;          // < 3145728
  const float4 v = ((const float4*)x)[i];
  ushort4 h, l;
  split2(v.x, h.x, l.x);
  split2(v.y, h.y, l.y);
  split2(v.z, h.z, l.z);
  split2(v.w, h.w, l.w);
  ((ushort4*)xh)[i] = h;
  ((ushort4*)xl)[i] = l;
}

// BT1[1536][2304]: col c -> head h=c>>7, group g=(c>>6)&1 (0=Q,1=K), d=c&63.
// k: seg 0 = W_hi, seg 1 = W_lo, seg 2 = W_hi  (pairs with A_ext = [Xh|Xh|Xl]).
// Q scale folds 1/sqrt(D) AND log2(e): flash softmax runs in exp2 domain.
__global__ __launch_bounds__(256) void pack_bt1_k(const float* __restrict__ Wq,
                                                  const float* __restrict__ Wk,
                                                  u16* __restrict__ BT1){
  int i = blockIdx.x*256 + threadIdx.x;          // < 3538944
  int c = i / 2304, k = i - c*2304;
  int seg = (k >= 768) + (k >= 1536);
  int e = k - seg*768;
  int h = c >> 7, g = (c >> 6) & 1, d = c & 63;
  const float* W = g ? Wk : Wq;
  float v = W[((size_t)h*EE + e)*DD + d] * (g ? 1.0f : 0.125f*1.4426950408889634f);
  u16 hi, lo; split2(v, hi, lo);
  BT1[i] = (seg == 1) ? lo : hi;
}

// BT2[768][768]: col c -> h=c>>6, d=c&63; k=e. Plain bf16.
__global__ __launch_bounds__(256) void pack_bt2_k(const float* __restrict__ Wv,
                                                  u16* __restrict__ BT2){
  int i = blockIdx.x*256 + threadIdx.x;          // < 589824
  int c = i / 768, e = i - c*768;
  int h = c >> 6, d = c & 63;
  BT2[i] = f2bf(Wv[((size_t)h*EE + e)*DD + d]);
}

__global__ __launch_bounds__(256) void pack_wo_k(const float* __restrict__ W, u16* __restrict__ Wt){
  int i = blockIdx.x*256 + threadIdx.x;          // < 49152
  int j = i & 63, k = i >> 6;
  Wt[(size_t)j*EE + k] = f2bf(W[i]);
}

// ---------------- big staged GEMM (m97-style 2-phase, 128x128 tile, BK=64) ----------------
// MODE0 epilogue: C cols split bf16 hi/lo -> (Qh,Ql) [wc=0] / (Kh,Kl) [wc=1].
// MODE1 epilogue: V bf16 -> Vt[h*16+b][d][kv'] with kv' pre-permuted for flash PV frags:
//   within each 64-kv group: kv = 16*(j>>2) + 4*lg + (j&3) + 32*ks  stored at  ks*32+lg*8+j.
template<int KT, int MODE>
__global__ __launch_bounds__(256) void gemm_big_k(const u16* __restrict__ Xh, const u16* __restrict__ Xl,
                                                  const u16* __restrict__ BT,
                                                  u16* __restrict__ O0h, u16* __restrict__ O0l,
                                                  u16* __restrict__ O1h, u16* __restrict__ O1l){
  __shared__ u16 lds[2][2][8192];                // [buf][A/B][128*64] = 64 KB
  constexpr int NB  = (MODE == 0) ? 12 : 6;      // col-tiles
  constexpr int CPX = (MODE == 0) ? 192 : 96;    // blocks per XCD chunk
  constexpr int KE  = KT*64;                     // B K-extent (elems)

  const int flat = blockIdx.x;
  const int swz = (flat & 7)*CPX + (flat >> 3);  // XCD-chunked, bc fastest (A-panel L2 reuse)
  const int rt = swz / NB, bc = swz - rt*NB;
  const int row0 = rt*128, col0 = bc*128;
  const int tid = threadIdx.x;
  const int w = tid >> 6, l = tid & 63, lr = l & 15, lg = l >> 4;
  const int wr = w >> 1, wc = w & 1;
  const int sr = l >> 3, sce = (l & 7)*8;        // staging: row-in-8, col elem

  f32x4 acc[4][4];
  #pragma unroll
  for (int m=0;m<4;++m)
    #pragma unroll
    for (int n=0;n<4;++n) acc[m][n] = f32x4{0.f,0.f,0.f,0.f};

  auto stage = [&](int buf, int kt){
    const u16* asrc = (MODE == 0 && kt >= 24) ? Xl : Xh;
    const int e0 = (MODE == 0) ? (kt - (kt >= 24 ? 24 : (kt >= 12 ? 12 : 0)))*64 : kt*64;
    const u16* ab = asrc + (size_t)row0*EE + e0 + sce;
    const u16* bb = BT + (size_t)col0*KE + kt*64 + sce;
    u16* la = &lds[buf][0][0];
    u16* lb = &lds[buf][1][0];
    #pragma unroll
    for (int j=0;j<4;++j){
      const int it = j*4 + w;                    // 16 sub-blocks of 8 rows
      stage16(ab + (size_t)(it*8 + sr)*EE, la + it*512);
      stage16(bb + (size_t)(it*8 + sr)*KE, lb + it*512);
    }
  };

  stage(0, 0);
  __syncthreads();

  for (int kt=0; kt<KT; ++kt){
    const int buf = kt & 1;
    if (kt + 1 < KT) stage(buf ^ 1, kt + 1);

    const u16* la = &lds[buf][0][0];
    const u16* lb = &lds[buf][1][0];
    bf16x8 af[4][2], bfr[4][2];
    #pragma unroll
    for (int m=0;m<4;++m)
      #pragma unroll
      for (int ks=0;ks<2;++ks)
        af[m][ks] = ld8(la + (wr*64 + m*16 + lr)*64 + ks*32 + lg*8);
    #pragma unroll
    for (int n=0;n<4;++n)
      #pragma unroll
      for (int ks=0;ks<2;++ks)
        bfr[n][ks] = ld8(lb + (wc*64 + n*16 + lr)*64 + ks*32 + lg*8);

    #pragma unroll
    for (int ks=0;ks<2;++ks)
      #pragma unroll
      for (int m=0;m<4;++m)
        #pragma unroll
        for (int n=0;n<4;++n)
          acc[m][n] = mfma16(af[m][ks], bfr[n][ks], acc[m][n]);

    __syncthreads();   // drains vmcnt (stage done) + all waves done reading buf
  }

  if constexpr (MODE == 0){
    u16* Dh = wc ? O1h : O0h;
    u16* Dl = wc ? O1l : O0l;
    const size_t base = (size_t)bc*BN*DD;        // head = bc
    #pragma unroll
    for (int m=0;m<4;++m)
      #pragma unroll
      for (int n=0;n<4;++n)
        #pragma unroll
        for (int j=0;j<4;++j){
          int r = row0 + wr*64 + m*16 + lg*4 + j;
          int d = n*16 + lr;
          size_t o = base + (size_t)r*DD + d;
          u16 hi, lo; split2(acc[m][n][j], hi, lo);
          Dh[o] = hi; Dl[o] = lo;
        }
  } else {
    #pragma unroll
    for (int m=0;m<4;++m)
      #pragma unroll
      for (int n=0;n<4;++n){
        int c = col0 + wc*64 + n*16 + lr;
        int hh = c >> 6, d = c & 63;
        int r = row0 + wr*64 + m*16 + lg*4;
        int b = r >> 10, nn = r & 1023;
        // pre-permuted kv offset: nn..nn+3 -> group base + ks*32 + lg'*8 + jh*4 .. +3
        int kvb = nn & ~63, kvL = nn & 63;
        int ks = kvL >> 5, rem = kvL & 31;
        int lgp = (rem >> 2) & 3, jh = rem >> 4;
        int off = kvb + ks*32 + lgp*8 + jh*4;
        ushort4 pk;
        pk.x = f2bf(acc[m][n][0]); pk.y = f2bf(acc[m][n][1]);
        pk.z = f2bf(acc[m][n][2]); pk.w = f2bf(acc[m][n][3]);
        *(ushort4*)(O0h + ((size_t)((hh*16 + b)*DD + d))*NN + off) = pk;
      }
  }
}

// ---------------- flash attention v7: 8-wave blocks, 3-pass bf16 QK, LDS-staged K ----------------
// 8 waves x 32 q-rows = 256 q/block; K hi/lo double-buffered in LDS (global_load_lds,
// pre-swizzled source, XOR-swizzled b128 reads), staged once per block for all 8 waves.
// Swapped-operand QK (lane owns q-col), exp2-domain softmax, lazy group rescale,
// per-lane partial ls, V loaded as single dwordx4 from pre-permuted Vt.
__global__ __launch_bounds__(512) void flash_k(const u16* __restrict__ Qh, const u16* __restrict__ Ql,
                                               const u16* __restrict__ Kh, const u16* __restrict__ Kl,
                                               const u16* __restrict__ Vt, u16* __restrict__ Cc){
  __shared__ u16 kbuf[2][2][4096];                 // [buf][hi/lo][64*64] = 32 KB
  const int flat = blockIdx.x;                     // 768 = 8 XCD * 96
  const int swz = (flat & 7)*96 + (flat >> 3);     // XCD chunking: all blocks of a (b,h) share L2
  const int qb = swz & 3, bh = swz >> 2;
  const int h = bh % 12, b = bh / 12;
  const int l = threadIdx.x & 63, w = threadIdx.x >> 6, lr = l & 15, lg = l >> 4;
  const size_t hb = (size_t)h*BN*DD + (size_t)b*NN*DD;
  const size_t vtb = (size_t)((h*16 + b)*DD);
  const int q0 = qb*256 + w*32;

  // staging geometry: chunk = 8 rows x 128B; lane l covers row (l>>3), swizzled col 8*((l&7)^(l>>3))
  const int srow = l >> 3;
  const int scol = 8*((l & 7) ^ srow);

  auto stage = [&](int buf, int t){
    const int kv0 = t*64;
    #pragma unroll
    for (int j=0;j<2;++j){
      const int c = w*2 + j;                       // 16 chunks over 8 waves: 0-7 Kh, 8-15 Kl
      const u16* src = (c < 8) ? Kh : Kl;
      const int cr = (c & 7)*8;
      stage16(src + hb + (size_t)(kv0 + cr + srow)*DD + scol,
              &kbuf[buf][c >> 3][(c & 7)*512]);
    }
  };

  // hoist Q B-frags (col = lr -> q, k = lg*8 contiguous along D)
  bf16x8 qfh[2][2], qfl[2][2];
  #pragma unroll
  for (int qf=0;qf<2;++qf)
    #pragma unroll
    for (int ks=0;ks<2;++ks){
      size_t o = hb + (size_t)(q0 + qf*16 + lr)*DD + ks*32 + lg*8;
      qfh[qf][ks] = ld8(Qh + o);
      qfl[qf][ks] = ld8(Ql + o);
    }

  f32x4 acc[2][4];                 // [qf][df] : O^T frags (row=d, col=q)
  float mr[2] = {-1e30f,-1e30f}, ls[2] = {0.f,0.f};   // ls = per-lane partial
  #pragma unroll
  for (int qf=0;qf<2;++qf)
    #pragma unroll
    for (int df=0;df<4;++df) acc[qf][df] = f32x4{0.f,0.f,0.f,0.f};

  stage(0, 0);
  __syncthreads();

  for (int t=0;t<16;++t){
    const int buf = t & 1;
    const int kv0 = t*64;

    // V^T A-frags first (oldest vmem ops); pre-permuted Vt -> one dwordx4 per frag
    bf16x8 va[4][2];
    #pragma unroll
    for (int df=0;df<4;++df)
      #pragma unroll
      for (int ks=0;ks<2;++ks)
        va[df][ks] = ld8(Vt + (vtb + df*16 + lr)*NN + kv0 + ks*32 + lg*8);

    if (t + 1 < 16) stage(buf ^ 1, t + 1);         // prefetch next K tile (hides under softmax+PV)

    // QK^T from LDS (swapped, 3-pass bf16 hi/lo)
    f32x4 s[2][4];                 // [qf][kf]
    #pragma unroll
    for (int qf=0;qf<2;++qf)
      #pragma unroll
      for (int kf=0;kf<4;++kf) s[qf][kf] = f32x4{0.f,0.f,0.f,0.f};

    const char* kb = (const char*)&kbuf[buf][0][0];
    #pragma unroll
    for (int ks=0;ks<2;++ks){
      bf16x8 kh[4], kl2[4];
      #pragma unroll
      for (int kf=0;kf<4;++kf){
        const int r = kf*16 + lr;
        const int sw = (ks*64 + lg*16) ^ ((lr & 7) << 4);
        kh[kf]  = *(const bf16x8*)(kb + r*128 + sw);
        kl2[kf] = *(const bf16x8*)(kb + 8192 + r*128 + sw);
      }
      __builtin_amdgcn_s_setprio(1);
      #pragma unroll
      for (int qf=0;qf<2;++qf)
        #pragma unroll
        for (int kf=0;kf<4;++kf){
          s[qf][kf] = mfma16(kh[kf],  qfh[qf][ks], s[qf][kf]);
          s[qf][kf] = mfma16(kl2[kf], qfh[qf][ks], s[qf][kf]);
          s[qf][kf] = mfma16(kh[kf],  qfl[qf][ks], s[qf][kf]);
        }
      __builtin_amdgcn_s_setprio(0);
    }

    // softmax (exp2 domain; lazy group rescale; per lane: 2 q-rows)
    bf16x8 pb[2][2];
    #pragma unroll
    for (int qf=0;qf<2;++qf){
      // lane-local max of this lane's 16 scores
      float a0 = fmaxf(fmaxf(s[qf][0][0], s[qf][0][1]), fmaxf(s[qf][0][2], s[qf][0][3]));
      float a1 = fmaxf(fmaxf(s[qf][1][0], s[qf][1][1]), fmaxf(s[qf][1][2], s[qf][1][3]));
      float a2 = fmaxf(fmaxf(s[qf][2][0], s[qf][2][1]), fmaxf(s[qf][2][2], s[qf][2][3]));
      float a3 = fmaxf(fmaxf(s[qf][3][0], s[qf][3][1]), fmaxf(s[qf][3][2], s[qf][3][3]));
      float pm = fmaxf(fmaxf(a0, a1), fmaxf(a2, a3));
      if (__any(pm > mr[qf] + 8.f)){               // rare: true max growth -> full rescale
        pm = fmaxf(pm, __shfl_xor(pm, 16, 64));    // group max (4 lanes share a q-column)
        pm = fmaxf(pm, __shfl_xor(pm, 32, 64));
        const float mn = fmaxf(mr[qf], pm);
        const float fs = exp2f(mr[qf] - mn);
        mr[qf] = mn;
        ls[qf] *= fs;
        #pragma unroll
        for (int df=0;df<4;++df)
          #pragma unroll
          for (int r=0;r<4;++r) acc[qf][df][r] *= fs;
      }
      float rs = 0.f;
      #pragma unroll
      for (int kf=0;kf<4;++kf)
        #pragma unroll
        for (int r=0;r<4;++r){
          float e = exp2f(s[qf][kf][r] - mr[qf]);  // bounded by 2^8
          s[qf][kf][r] = e;
          rs += e;
        }
      ls[qf] += rs;                                // per-lane partial
      // pack P as PV B-frag, k-permuted: elem j <- s[qf][2ks + (j>>2)][j&3]
      #pragma unroll
      for (int ks=0;ks<2;++ks){
        U8 pu;
        pu.w[0] = pk2(s[qf][2*ks][0],   s[qf][2*ks][1]);
        pu.w[1] = pk2(s[qf][2*ks][2],   s[qf][2*ks][3]);
        pu.w[2] = pk2(s[qf][2*ks+1][0], s[qf][2*ks+1][1]);
        pu.w[3] = pk2(s[qf][2*ks+1][2], s[qf][2*ks+1][3]);
        pb[qf][ks] = pu.v;
      }
    }

    // PV: O^T += V^T * P  (bf16)
    __builtin_amdgcn_s_setprio(1);
    #pragma unroll
    for (int ks=0;ks<2;++ks)
      #pragma unroll
      for (int qf=0;qf<2;++qf)
        #pragma unroll
        for (int df=0;df<4;++df)
          acc[qf][df] = mfma16(va[df][ks], pb[qf][ks], acc[qf][df]);
    __builtin_amdgcn_s_setprio(0);

    __syncthreads();               // stage(t+1) drained; all waves done with kbuf[buf]
  }

  // epilogue: reduce ls across the 4 lane-groups, normalize, write concat
  #pragma unroll
  for (int qf=0;qf<2;++qf){
    float t1 = ls[qf] + __shfl_xor(ls[qf], 16, 64);
    t1 += __shfl_xor(t1, 32, 64);
    const float inv = 1.0f / t1;
    #pragma unroll
    for (int df=0;df<4;++df){
      ushort4 o4;
      o4.x = f2bf(acc[qf][df][0]*inv);
      o4.y = f2bf(acc[qf][df][1]*inv);
      o4.z = f2bf(acc[qf][df][2]*inv);
      o4.w = f2bf(acc[qf][df][3]*inv);
      *(ushort4*)(Cc + (size_t)(b*NN + q0 + qf*16 + lr)*EE + h*DD + df*16 + lg*4) = o4;
    }
  }
}

// ---------------- output projection ----------------
__global__ __launch_bounds__(256) void gemm_o_k(const u16* __restrict__ Cc, const u16* __restrict__ Wot,
                                                float* __restrict__ out){
  const int rt = blockIdx.x;
  const int w = threadIdx.x >> 6, l = threadIdx.x & 63, lr = l & 15, lg = l >> 4;
  const int row0 = rt*64 + w*16;
  f32x4 acc[4];
  #pragma unroll
  for (int n=0;n<4;++n) acc[n] = f32x4{0.f,0.f,0.f,0.f};

  for (int kt=0; kt<12; ++kt){
    const int e0 = kt*64;
    bf16x8 a[2], bb[4][2];
    #pragma unroll
    for (int ks=0;ks<2;++ks)
      a[ks] = ld8(Cc + (size_t)(row0 + lr)*EE + e0 + ks*32 + lg*8);
    #pragma unroll
    for (int nf=0;nf<4;++nf)
      #pragma unroll
      for (int ks=0;ks<2;++ks)
        bb[nf][ks] = ld8(Wot + (size_t)(nf*16 + lr)*EE + e0 + ks*32 + lg*8);
    #pragma unroll
    for (int ks=0;ks<2;++ks)
      #pragma unroll
      for (int nf=0;nf<4;++nf)
        acc[nf] = mfma16(a[ks], bb[nf][ks], acc[nf]);
  }
  #pragma unroll
  for (int nf=0;nf<4;++nf)
    #pragma unroll
    for (int j=0;j<4;++j)
      out[(size_t)(row0 + lg*4 + j)*DD + nf*16 + lr] = acc[nf][j];
}

// ---------------- launch ----------------
extern "C" void kernel_launch(void* const* d_in, const int* in_sizes, int n_in,
                              void* d_out, int out_size, void* d_ws, size_t ws_size,
                              hipStream_t stream) {
  const float* x  = (const float*)d_in[0];
  const float* Wq = (const float*)d_in[1];
  const float* Wk = (const float*)d_in[2];
  const float* Wv = (const float*)d_in[3];
  const float* Wo = (const float*)d_in[4];
  float* out = (float*)d_out;

  u16* ws = (u16*)d_ws;
  const size_t SB = (size_t)12582912;   // 16384*768
  u16* Xh  = ws;
  u16* Xl  = Xh + SB;
  u16* Qh  = Xl + SB;
  u16* Ql  = Qh + SB;
  u16* Kh  = Ql + SB;
  u16* Kl  = Kh + SB;
  u16* Vt  = Kl + SB;
  u16* Cc  = Vt + SB;
  u16* Wot = Cc + SB;
  // BT1/BT2 alias into Cc: written by packs, read by GEMMs, then Cc is fully
  // overwritten by flash_k before gemm_o_k reads it (in-stream ordering).
  u16* BT1 = Cc;                        // 1536*2304 = 3538944 elems
  u16* BT2 = Cc + 3538944;              // 768*768   =  589824 elems

  split_x_k <<<12288, 256, 0, stream>>>(x, Xh, Xl);
  pack_bt1_k<<<13824, 256, 0, stream>>>(Wq, Wk, BT1);
  pack_bt2_k<<<2304,  256, 0, stream>>>(Wv, BT2);
  pack_wo_k <<<192,   256, 0, stream>>>(Wo, Wot);

  gemm_big_k<36,0><<<1536, 256, 0, stream>>>(Xh, Xl, BT1, Qh, Ql, Kh, Kl);
  gemm_big_k<12,1><<<768,  256, 0, stream>>>(Xh, Xl, BT2, Vt, nullptr, nullptr, nullptr);
  flash_k   <<<768,  512, 0, stream>>>(Qh, Ql, Kh, Kl, Vt, Cc);
  gemm_o_k  <<<256,  256, 0, stream>>>(Cc, Wot, out);
}

// Round 9
// 337.371 us; speedup vs baseline: 1.4945x; 1.1235x over previous
//
#include <hip/hip_runtime.h>
#include <hip/hip_bf16.h>

typedef unsigned short u16;
typedef unsigned int u32;
typedef __attribute__((ext_vector_type(8))) short bf16x8;   // 8x16-bit in 4 VGPRs
typedef __attribute__((ext_vector_type(4))) float f32x4;

#define DEV static __device__ __forceinline__

#define BB 16
#define NN 1024
#define EE 768
#define HH 12
#define DD 64
#define BN (BB*NN)   // 16384

DEV u16 f2bf(float f){ __hip_bfloat16 h = __float2bfloat16(f); u16 u; __builtin_memcpy(&u, &h, 2); return u; }
DEV float bf2f(u16 u){ __hip_bfloat16 h; __builtin_memcpy(&h, &u, 2); return __bfloat162float(h); }
DEV void split2(float v, u16& hi, u16& lo){ hi = f2bf(v); lo = f2bf(v - bf2f(hi)); }
DEV bf16x8 ld8(const u16* p){ return *(const bf16x8*)p; }
DEV f32x4 mfma16(bf16x8 a, bf16x8 b, f32x4 c){ return __builtin_amdgcn_mfma_f32_16x16x32_bf16(a, b, c, 0, 0, 0); }
DEV u32 pk2(float a, float b){                       // 2xf32 -> packed 2xbf16 (v_cvt_pk_bf16_f32)
  float2 f{a, b};
  __hip_bfloat162 t = __float22bfloat162_rn(f);
  u32 r; __builtin_memcpy(&r, &t, 4); return r;
}

union U8 { bf16x8 v; u16 e[8]; ushort4 q[2]; u32 w[4]; };

// async global->LDS, 16B per lane. LDS dst must be wave-uniform; HW adds lane*16.
DEV void stage16(const u16* g, u16* l){
  __builtin_amdgcn_global_load_lds((const __attribute__((address_space(1))) void*)g,
                                   (__attribute__((address_space(3))) void*)l,
                                   16, 0, 0);
}

// ---------------- prep kernels ----------------

__global__ __launch_bounds__(256) void split_x_k(const float* __restrict__ x,
                                                 u16* __restrict__ xh, u16* __restrict__ xl){
  int i = blockIdx.x*256 + threadIdx.x;          // < 3145728
  const float4 v = ((const float4*)x)[i];
  ushort4 h, l;
  split2(v.x, h.x, l.x);
  split2(v.y, h.y, l.y);
  split2(v.z, h.z, l.z);
  split2(v.w, h.w, l.w);
  ((ushort4*)xh)[i] = h;
  ((ushort4*)xl)[i] = l;
}

// BT1[1536][1536]: row c -> head h=c>>7, group g=(c>>6)&1 (0=Q,1=K), d=c&63.
// col k: k<768 -> W_hi(e=k), k>=768 -> W_lo(e=k-768).
// Q scale folds 1/sqrt(D) AND log2(e): flash softmax runs in exp2 domain.
__global__ __launch_bounds__(256) void pack_bt1_k(const float* __restrict__ Wq,
                                                  const float* __restrict__ Wk,
                                                  u16* __restrict__ BT1){
  int i = blockIdx.x*256 + threadIdx.x;          // < 2359296
  int c = i / 1536, k = i - c*1536;
  int seg = (k >= 768);
  int e = k - seg*768;
  int h = c >> 7, g = (c >> 6) & 1, d = c & 63;
  const float* W = g ? Wk : Wq;
  float v = W[((size_t)h*EE + e)*DD + d] * (g ? 1.0f : 0.125f*1.4426950408889634f);
  u16 hi, lo; split2(v, hi, lo);
  BT1[i] = seg ? lo : hi;
}

// BT2[768][768]: col c -> h=c>>6, d=c&63; k=e. Plain bf16.
__global__ __launch_bounds__(256) void pack_bt2_k(const float* __restrict__ Wv,
                                                  u16* __restrict__ BT2){
  int i = blockIdx.x*256 + threadIdx.x;          // < 589824
  int c = i / 768, e = i - c*768;
  int h = c >> 6, d = c & 63;
  BT2[i] = f2bf(Wv[((size_t)h*EE + e)*DD + d]);
}

__global__ __launch_bounds__(256) void pack_wo_k(const float* __restrict__ W, u16* __restrict__ Wt){
  int i = blockIdx.x*256 + threadIdx.x;          // < 49152
  int j = i & 63, k = i >> 6;
  Wt[(size_t)j*EE + k] = f2bf(W[i]);
}

// ---------------- Q/K projection GEMM (A-reuse, BK=32, 24 iters) ----------------
// Per iter stages 4 panels {Xh,Xl,Wh,Wl}[128x32] (dbuf, 64 KB LDS) and issues the
// 3 cross-products Xh*Wh + Xh*Wl + Xl*Wh. Epilogue: bf16 hi/lo split -> Q (wc=0), K (wc=1).
__global__ __launch_bounds__(256) void gemm_qk_k(const u16* __restrict__ Xh, const u16* __restrict__ Xl,
                                                 const u16* __restrict__ BT1,
                                                 u16* __restrict__ Qh, u16* __restrict__ Ql,
                                                 u16* __restrict__ Kh, u16* __restrict__ Kl){
  __shared__ u16 lds[2][4][4096];                // [buf][Xh,Xl,Wh,Wl][128*32] = 64 KB
  const int flat = blockIdx.x;                   // 1536 = 8 XCD * 192
  const int swz = (flat & 7)*192 + (flat >> 3);  // XCD-chunked, bc fastest (A-panel L2 reuse)
  const int rt = swz / 12, bc = swz - rt*12;
  const int row0 = rt*128, col0 = bc*128;
  const int tid = threadIdx.x;
  const int w = tid >> 6, l = tid & 63, lr = l & 15, lg = l >> 4;
  const int wr = w >> 1, wc = w & 1;
  const int sr = l >> 2, sce = (l & 3)*8;        // staging: 16 rows/wave-round, 32-col rows

  f32x4 acc[4][4];
  #pragma unroll
  for (int m=0;m<4;++m)
    #pragma unroll
    for (int n=0;n<4;++n) acc[m][n] = f32x4{0.f,0.f,0.f,0.f};

  auto stage = [&](int buf, int kt){
    const int e0 = kt*32;
    #pragma unroll
    for (int j=0;j<2;++j){
      const int r = w*32 + j*16;                 // wave-round row base
      const int gr = r + sr;                     // this lane's row
      u16* dst0 = &lds[buf][0][r*32];
      u16* dst1 = &lds[buf][1][r*32];
      u16* dst2 = &lds[buf][2][r*32];
      u16* dst3 = &lds[buf][3][r*32];
      stage16(Xh  + (size_t)(row0 + gr)*EE   + e0 + sce,        dst0);
      stage16(Xl  + (size_t)(row0 + gr)*EE   + e0 + sce,        dst1);
      stage16(BT1 + (size_t)(col0 + gr)*1536 + e0 + sce,        dst2);
      stage16(BT1 + (size_t)(col0 + gr)*1536 + 768 + e0 + sce,  dst3);
    }
  };

  stage(0, 0);
  __syncthreads();

  for (int kt=0; kt<24; ++kt){
    const int buf = kt & 1;
    if (kt + 1 < 24) stage(buf ^ 1, kt + 1);

    bf16x8 ah[4], al[4], bh[4], bl[4];
    #pragma unroll
    for (int m=0;m<4;++m){
      const int off = (wr*64 + m*16 + lr)*32 + lg*8;
      ah[m] = ld8(&lds[buf][0][off]);
      al[m] = ld8(&lds[buf][1][off]);
    }
    #pragma unroll
    for (int n=0;n<4;++n){
      const int off = (wc*64 + n*16 + lr)*32 + lg*8;
      bh[n] = ld8(&lds[buf][2][off]);
      bl[n] = ld8(&lds[buf][3][off]);
    }

    __builtin_amdgcn_s_setprio(1);
    #pragma unroll
    for (int m=0;m<4;++m)
      #pragma unroll
      for (int n=0;n<4;++n){
        acc[m][n] = mfma16(ah[m], bh[n], acc[m][n]);
        acc[m][n] = mfma16(ah[m], bl[n], acc[m][n]);
        acc[m][n] = mfma16(al[m], bh[n], acc[m][n]);
      }
    __builtin_amdgcn_s_setprio(0);

    __syncthreads();   // drains vmcnt (stage done) + all waves done reading buf
  }

  u16* Dh = wc ? Kh : Qh;
  u16* Dl = wc ? Kl : Ql;
  const size_t base = (size_t)bc*BN*DD;          // head = bc
  #pragma unroll
  for (int m=0;m<4;++m)
    #pragma unroll
    for (int n=0;n<4;++n)
      #pragma unroll
      for (int j=0;j<4;++j){
        int r = row0 + wr*64 + m*16 + lg*4 + j;
        int d = n*16 + lr;
        size_t o = base + (size_t)r*DD + d;
        u16 hi, lo; split2(acc[m][n][j], hi, lo);
        Dh[o] = hi; Dl[o] = lo;
      }
}

// ---------------- V projection GEMM (staged, 128x128 tile, BK=64) ----------------
// Epilogue: V bf16 -> Vt[h*16+b][d][kv'] with kv' pre-permuted for flash PV frags.
__global__ __launch_bounds__(256) void gemm_v_k(const u16* __restrict__ Xh,
                                                const u16* __restrict__ BT,
                                                u16* __restrict__ Vt){
  __shared__ u16 lds[2][2][8192];                // [buf][A/B][128*64] = 64 KB
  const int flat = blockIdx.x;                   // 768 = 8 XCD * 96
  const int swz = (flat & 7)*96 + (flat >> 3);
  const int rt = swz / 6, bc = swz - rt*6;
  const int row0 = rt*128, col0 = bc*128;
  const int tid = threadIdx.x;
  const int w = tid >> 6, l = tid & 63, lr = l & 15, lg = l >> 4;
  const int wr = w >> 1, wc = w & 1;
  const int sr = l >> 3, sce = (l & 7)*8;

  f32x4 acc[4][4];
  #pragma unroll
  for (int m=0;m<4;++m)
    #pragma unroll
    for (int n=0;n<4;++n) acc[m][n] = f32x4{0.f,0.f,0.f,0.f};

  auto stage = [&](int buf, int kt){
    const int e0 = kt*64;
    const u16* ab = Xh + (size_t)row0*EE + e0 + sce;
    const u16* bb = BT + (size_t)col0*EE + e0 + sce;
    u16* la = &lds[buf][0][0];
    u16* lb = &lds[buf][1][0];
    #pragma unroll
    for (int j=0;j<4;++j){
      const int it = j*4 + w;
      stage16(ab + (size_t)(it*8 + sr)*EE, la + it*512);
      stage16(bb + (size_t)(it*8 + sr)*EE, lb + it*512);
    }
  };

  stage(0, 0);
  __syncthreads();

  for (int kt=0; kt<12; ++kt){
    const int buf = kt & 1;
    if (kt + 1 < 12) stage(buf ^ 1, kt + 1);

    const u16* la = &lds[buf][0][0];
    const u16* lb = &lds[buf][1][0];
    bf16x8 af[4][2], bfr[4][2];
    #pragma unroll
    for (int m=0;m<4;++m)
      #pragma unroll
      for (int ks=0;ks<2;++ks)
        af[m][ks] = ld8(la + (wr*64 + m*16 + lr)*64 + ks*32 + lg*8);
    #pragma unroll
    for (int n=0;n<4;++n)
      #pragma unroll
      for (int ks=0;ks<2;++ks)
        bfr[n][ks] = ld8(lb + (wc*64 + n*16 + lr)*64 + ks*32 + lg*8);

    #pragma unroll
    for (int ks=0;ks<2;++ks)
      #pragma unroll
      for (int m=0;m<4;++m)
        #pragma unroll
        for (int n=0;n<4;++n)
          acc[m][n] = mfma16(af[m][ks], bfr[n][ks], acc[m][n]);

    __syncthreads();
  }

  #pragma unroll
  for (int m=0;m<4;++m)
    #pragma unroll
    for (int n=0;n<4;++n){
      int c = col0 + wc*64 + n*16 + lr;
      int hh = c >> 6, d = c & 63;
      int r = row0 + wr*64 + m*16 + lg*4;
      int b = r >> 10, nn = r & 1023;
      // pre-permuted kv offset: nn..nn+3 -> group base + ks*32 + lg'*8 + jh*4 .. +3
      int kvb = nn & ~63, kvL = nn & 63;
      int ks = kvL >> 5, rem = kvL & 31;
      int lgp = (rem >> 2) & 3, jh = rem >> 4;
      int off = kvb + ks*32 + lgp*8 + jh*4;
      ushort4 pk;
      pk.x = f2bf(acc[m][n][0]); pk.y = f2bf(acc[m][n][1]);
      pk.z = f2bf(acc[m][n][2]); pk.w = f2bf(acc[m][n][3]);
      *(ushort4*)(Vt + ((size_t)((hh*16 + b)*DD + d))*NN + off) = pk;
    }
}

// ---------------- flash attention: 8-wave blocks, 3-pass bf16 QK, LDS-staged K ----------------
__global__ __launch_bounds__(512) void flash_k(const u16* __restrict__ Qh, const u16* __restrict__ Ql,
                                               const u16* __restrict__ Kh, const u16* __restrict__ Kl,
                                               const u16* __restrict__ Vt, u16* __restrict__ Cc){
  __shared__ u16 kbuf[2][2][4096];                 // [buf][hi/lo][64*64] = 32 KB
  const int flat = blockIdx.x;                     // 768 = 8 XCD * 96
  const int swz = (flat & 7)*96 + (flat >> 3);     // XCD chunking: all blocks of a (b,h) share L2
  const int qb = swz & 3, bh = swz >> 2;
  const int h = bh % 12, b = bh / 12;
  const int l = threadIdx.x & 63, w = threadIdx.x >> 6, lr = l & 15, lg = l >> 4;
  const size_t hb = (size_t)h*BN*DD + (size_t)b*NN*DD;
  const size_t vtb = (size_t)((h*16 + b)*DD);
  const int q0 = qb*256 + w*32;

  const int srow = l >> 3;
  const int scol = 8*((l & 7) ^ srow);

  auto stage = [&](int buf, int t){
    const int kv0 = t*64;
    #pragma unroll
    for (int j=0;j<2;++j){
      const int c = w*2 + j;                       // 16 chunks over 8 waves: 0-7 Kh, 8-15 Kl
      const u16* src = (c < 8) ? Kh : Kl;
      const int cr = (c & 7)*8;
      stage16(src + hb + (size_t)(kv0 + cr + srow)*DD + scol,
              &kbuf[buf][c >> 3][(c & 7)*512]);
    }
  };

  bf16x8 qfh[2][2], qfl[2][2];
  #pragma unroll
  for (int qf=0;qf<2;++qf)
    #pragma unroll
    for (int ks=0;ks<2;++ks){
      size_t o = hb + (size_t)(q0 + qf*16 + lr)*DD + ks*32 + lg*8;
      qfh[qf][ks] = ld8(Qh + o);
      qfl[qf][ks] = ld8(Ql + o);
    }

  f32x4 acc[2][4];                 // [qf][df] : O^T frags (row=d, col=q)
  float mr[2] = {-1e30f,-1e30f}, ls[2] = {0.f,0.f};   // ls = per-lane partial
  #pragma unroll
  for (int qf=0;qf<2;++qf)
    #pragma unroll
    for (int df=0;df<4;++df) acc[qf][df] = f32x4{0.f,0.f,0.f,0.f};

  stage(0, 0);
  __syncthreads();

  for (int t=0;t<16;++t){
    const int buf = t & 1;
    const int kv0 = t*64;

    // V^T A-frags first (oldest vmem ops); pre-permuted Vt -> one dwordx4 per frag
    bf16x8 va[4][2];
    #pragma unroll
    for (int df=0;df<4;++df)
      #pragma unroll
      for (int ks=0;ks<2;++ks)
        va[df][ks] = ld8(Vt + (vtb + df*16 + lr)*NN + kv0 + ks*32 + lg*8);

    if (t + 1 < 16) stage(buf ^ 1, t + 1);         // prefetch next K tile

    f32x4 s[2][4];                 // [qf][kf]
    #pragma unroll
    for (int qf=0;qf<2;++qf)
      #pragma unroll
      for (int kf=0;kf<4;++kf) s[qf][kf] = f32x4{0.f,0.f,0.f,0.f};

    const char* kb = (const char*)&kbuf[buf][0][0];
    #pragma unroll
    for (int ks=0;ks<2;++ks){
      bf16x8 kh[4], kl2[4];
      #pragma unroll
      for (int kf=0;kf<4;++kf){
        const int r = kf*16 + lr;
        const int sw = (ks*64 + lg*16) ^ ((lr & 7) << 4);
        kh[kf]  = *(const bf16x8*)(kb + r*128 + sw);
        kl2[kf] = *(const bf16x8*)(kb + 8192 + r*128 + sw);
      }
      __builtin_amdgcn_s_setprio(1);
      #pragma unroll
      for (int qf=0;qf<2;++qf)
        #pragma unroll
        for (int kf=0;kf<4;++kf){
          s[qf][kf] = mfma16(kh[kf],  qfh[qf][ks], s[qf][kf]);
          s[qf][kf] = mfma16(kl2[kf], qfh[qf][ks], s[qf][kf]);
          s[qf][kf] = mfma16(kh[kf],  qfl[qf][ks], s[qf][kf]);
        }
      __builtin_amdgcn_s_setprio(0);
    }

    // softmax (exp2 domain; lazy group rescale; per lane: 2 q-rows)
    bf16x8 pb[2][2];
    #pragma unroll
    for (int qf=0;qf<2;++qf){
      float a0 = fmaxf(fmaxf(s[qf][0][0], s[qf][0][1]), fmaxf(s[qf][0][2], s[qf][0][3]));
      float a1 = fmaxf(fmaxf(s[qf][1][0], s[qf][1][1]), fmaxf(s[qf][1][2], s[qf][1][3]));
      float a2 = fmaxf(fmaxf(s[qf][2][0], s[qf][2][1]), fmaxf(s[qf][2][2], s[qf][2][3]));
      float a3 = fmaxf(fmaxf(s[qf][3][0], s[qf][3][1]), fmaxf(s[qf][3][2], s[qf][3][3]));
      float pm = fmaxf(fmaxf(a0, a1), fmaxf(a2, a3));
      if (__any(pm > mr[qf] + 8.f)){               // rare: true max growth -> full rescale
        pm = fmaxf(pm, __shfl_xor(pm, 16, 64));
        pm = fmaxf(pm, __shfl_xor(pm, 32, 64));
        const float mn = fmaxf(mr[qf], pm);
        const float fs = exp2f(mr[qf] - mn);
        mr[qf] = mn;
        ls[qf] *= fs;
        #pragma unroll
        for (int df=0;df<4;++df)
          #pragma unroll
          for (int r=0;r<4;++r) acc[qf][df][r] *= fs;
      }
      float rs = 0.f;
      #pragma unroll
      for (int kf=0;kf<4;++kf)
        #pragma unroll
        for (int r=0;r<4;++r){
          float e = exp2f(s[qf][kf][r] - mr[qf]);  // bounded by 2^8
          s[qf][kf][r] = e;
          rs += e;
        }
      ls[qf] += rs;
      #pragma unroll
      for (int ks=0;ks<2;++ks){
        U8 pu;
        pu.w[0] = pk2(s[qf][2*ks][0],   s[qf][2*ks][1]);
        pu.w[1] = pk2(s[qf][2*ks][2],   s[qf][2*ks][3]);
        pu.w[2] = pk2(s[qf][2*ks+1][0], s[qf][2*ks+1][1]);
        pu.w[3] = pk2(s[qf][2*ks+1][2], s[qf][2*ks+1][3]);
        pb[qf][ks] = pu.v;
      }
    }

    // PV: O^T += V^T * P  (bf16)
    __builtin_amdgcn_s_setprio(1);
    #pragma unroll
    for (int ks=0;ks<2;++ks)
      #pragma unroll
      for (int qf=0;qf<2;++qf)
        #pragma unroll
        for (int df=0;df<4;++df)
          acc[qf][df] = mfma16(va[df][ks], pb[qf][ks], acc[qf][df]);
    __builtin_amdgcn_s_setprio(0);

    __syncthreads();
  }

  #pragma unroll
  for (int qf=0;qf<2;++qf){
    float t1 = ls[qf] + __shfl_xor(ls[qf], 16, 64);
    t1 += __shfl_xor(t1, 32, 64);
    const float inv = 1.0f / t1;
    #pragma unroll
    for (int df=0;df<4;++df){
      ushort4 o4;
      o4.x = f2bf(acc[qf][df][0]*inv);
      o4.y = f2bf(acc[qf][df][1]*inv);
      o4.z = f2bf(acc[qf][df][2]*inv);
      o4.w = f2bf(acc[qf][df][3]*inv);
      *(ushort4*)(Cc + (size_t)(b*NN + q0 + qf*16 + lr)*EE + h*DD + df*16 + lg*4) = o4;
    }
  }
}

// ---------------- output projection (staged, 64-row tiles, BK=64) ----------------
__global__ __launch_bounds__(256) void gemm_o_k(const u16* __restrict__ Cc, const u16* __restrict__ Wot,
                                                float* __restrict__ out){
  __shared__ u16 lds[2][2][4096];                // [buf][A/B][64*64] = 32 KB
  const int rt = blockIdx.x;                     // 256 blocks x 64 rows
  const int tid = threadIdx.x;
  const int w = tid >> 6, l = tid & 63, lr = l & 15, lg = l >> 4;
  const int row0 = rt*64;
  const int sr = l >> 3, sce = (l & 7)*8;        // staging: 8 rows/wave-round, 64-col rows

  f32x4 acc[4];
  #pragma unroll
  for (int n=0;n<4;++n) acc[n] = f32x4{0.f,0.f,0.f,0.f};

  auto stage = [&](int buf, int kt){
    const int e0 = kt*64;
    #pragma unroll
    for (int j=0;j<2;++j){
      const int r = w*16 + j*8;                  // wave-round row base
      stage16(Cc  + (size_t)(row0 + r + sr)*EE + e0 + sce, &lds[buf][0][r*64]);
      stage16(Wot + (size_t)(r + sr)*EE        + e0 + sce, &lds[buf][1][r*64]);
    }
  };

  stage(0, 0);
  __syncthreads();

  for (int kt=0; kt<12; ++kt){
    const int buf = kt & 1;
    if (kt + 1 < 12) stage(buf ^ 1, kt + 1);

    bf16x8 a[2], bb[4][2];
    #pragma unroll
    for (int ks=0;ks<2;++ks)
      a[ks] = ld8(&lds[buf][0][(w*16 + lr)*64 + ks*32 + lg*8]);
    #pragma unroll
    for (int nf=0;nf<4;++nf)
      #pragma unroll
      for (int ks=0;ks<2;++ks)
        bb[nf][ks] = ld8(&lds[buf][1][(nf*16 + lr)*64 + ks*32 + lg*8]);

    #pragma unroll
    for (int ks=0;ks<2;++ks)
      #pragma unroll
      for (int nf=0;nf<4;++nf)
        acc[nf] = mfma16(a[ks], bb[nf][ks], acc[nf]);

    __syncthreads();
  }

  #pragma unroll
  for (int nf=0;nf<4;++nf)
    #pragma unroll
    for (int j=0;j<4;++j)
      out[(size_t)(row0 + w*16 + lg*4 + j)*DD + nf*16 + lr] = acc[nf][j];
}

// ---------------- launch ----------------
extern "C" void kernel_launch(void* const* d_in, const int* in_sizes, int n_in,
                              void* d_out, int out_size, void* d_ws, size_t ws_size,
                              hipStream_t stream) {
  const float* x  = (const float*)d_in[0];
  const float* Wq = (const float*)d_in[1];
  const float* Wk = (const float*)d_in[2];
  const float* Wv = (const float*)d_in[3];
  const float* Wo = (const float*)d_in[4];
  float* out = (float*)d_out;

  u16* ws = (u16*)d_ws;
  const size_t SB = (size_t)12582912;   // 16384*768
  u16* Xh  = ws;
  u16* Xl  = Xh + SB;
  u16* Qh  = Xl + SB;
  u16* Ql  = Qh + SB;
  u16* Kh  = Ql + SB;
  u16* Kl  = Kh + SB;
  u16* Vt  = Kl + SB;
  u16* Cc  = Vt + SB;
  u16* Wot = Cc + SB;
  // BT1/BT2 alias into Cc: written by packs, read by GEMMs, then Cc is fully
  // overwritten by flash_k before gemm_o_k reads it (in-stream ordering).
  u16* BT1 = Cc;                        // 1536*1536 = 2359296 elems
  u16* BT2 = Cc + 2359296;              // 768*768   =  589824 elems

  split_x_k <<<12288, 256, 0, stream>>>(x, Xh, Xl);
  pack_bt1_k<<<9216,  256, 0, stream>>>(Wq, Wk, BT1);
  pack_bt2_k<<<2304,  256, 0, stream>>>(Wv, BT2);
  pack_wo_k <<<192,   256, 0, stream>>>(Wo, Wot);

  gemm_qk_k<<<1536, 256, 0, stream>>>(Xh, Xl, BT1, Qh, Ql, Kh, Kl);
  gemm_v_k <<<768,  256, 0, stream>>>(Xh, BT2, Vt);
  flash_k  <<<768,  512, 0, stream>>>(Qh, Ql, Kh, Kl, Vt, Cc);
  gemm_o_k <<<256,  256, 0, stream>>>(Cc, Wot, out);
}

// Round 10
// 311.947 us; speedup vs baseline: 1.6163x; 1.0815x over previous
//
#include <hip/hip_runtime.h>
#include <hip/hip_bf16.h>

typedef unsigned short u16;
typedef unsigned int u32;
typedef __attribute__((ext_vector_type(8))) short bf16x8;   // 8x16-bit in 4 VGPRs
typedef __attribute__((ext_vector_type(4))) float f32x4;

#define DEV static __device__ __forceinline__

#define BB 16
#define NN 1024
#define EE 768
#define HH 12
#define DD 64
#define BN (BB*NN)   // 16384

DEV u16 f2bf(float f){ __hip_bfloat16 h = __float2bfloat16(f); u16 u; __builtin_memcpy(&u, &h, 2); return u; }
DEV float bf2f(u16 u){ __hip_bfloat16 h; __builtin_memcpy(&h, &u, 2); return __bfloat162float(h); }
DEV void split2(float v, u16& hi, u16& lo){ hi = f2bf(v); lo = f2bf(v - bf2f(hi)); }
DEV bf16x8 ld8(const u16* p){ return *(const bf16x8*)p; }
DEV f32x4 mfma16(bf16x8 a, bf16x8 b, f32x4 c){ return __builtin_amdgcn_mfma_f32_16x16x32_bf16(a, b, c, 0, 0, 0); }
DEV float fexp2(float x){ return __builtin_amdgcn_exp2f(x); }   // raw v_exp_f32; underflow->0 is wanted
DEV u32 pk2(float a, float b){                       // 2xf32 -> packed 2xbf16 (v_cvt_pk_bf16_f32)
  float2 f{a, b};
  __hip_bfloat162 t = __float22bfloat162_rn(f);
  u32 r; __builtin_memcpy(&r, &t, 4); return r;
}

union U8 { bf16x8 v; u16 e[8]; ushort4 q[2]; u32 w[4]; };

// async global->LDS, 16B per lane. LDS dst must be wave-uniform; HW adds lane*16.
DEV void stage16(const u16* g, u16* l){
  __builtin_amdgcn_global_load_lds((const __attribute__((address_space(1))) void*)g,
                                   (__attribute__((address_space(3))) void*)l,
                                   16, 0, 0);
}

// ---------------- prep kernels ----------------

__global__ __launch_bounds__(256) void split_x_k(const float* __restrict__ x,
                                                 u16* __restrict__ xh, u16* __restrict__ xl){
  int i = blockIdx.x*256 + threadIdx.x;          // < 3145728
  const float4 v = ((const float4*)x)[i];
  ushort4 h, l;
  split2(v.x, h.x, l.x);
  split2(v.y, h.y, l.y);
  split2(v.z, h.z, l.z);
  split2(v.w, h.w, l.w);
  ((ushort4*)xh)[i] = h;
  ((ushort4*)xl)[i] = l;
}

// BT1[1536][1536]: row c -> head h=c>>7, group g=(c>>6)&1 (0=Q,1=K), d=c&63.
// col k: k<768 -> W_hi(e=k), k>=768 -> W_lo(e=k-768).
// Q scale folds 1/sqrt(D) AND log2(e): flash softmax runs in exp2 domain.
__global__ __launch_bounds__(256) void pack_bt1_k(const float* __restrict__ Wq,
                                                  const float* __restrict__ Wk,
                                                  u16* __restrict__ BT1){
  int i = blockIdx.x*256 + threadIdx.x;          // < 2359296
  int c = i / 1536, k = i - c*1536;
  int seg = (k >= 768);
  int e = k - seg*768;
  int h = c >> 7, g = (c >> 6) & 1, d = c & 63;
  const float* W = g ? Wk : Wq;
  float v = W[((size_t)h*EE + e)*DD + d] * (g ? 1.0f : 0.125f*1.4426950408889634f);
  u16 hi, lo; split2(v, hi, lo);
  BT1[i] = seg ? lo : hi;
}

// BT2[768][768]: col c -> h=c>>6, d=c&63; k=e. Plain bf16.
__global__ __launch_bounds__(256) void pack_bt2_k(const float* __restrict__ Wv,
                                                  u16* __restrict__ BT2){
  int i = blockIdx.x*256 + threadIdx.x;          // < 589824
  int c = i / 768, e = i - c*768;
  int h = c >> 6, d = c & 63;
  BT2[i] = f2bf(Wv[((size_t)h*EE + e)*DD + d]);
}

__global__ __launch_bounds__(256) void pack_wo_k(const float* __restrict__ W, u16* __restrict__ Wt){
  int i = blockIdx.x*256 + threadIdx.x;          // < 49152
  int j = i & 63, k = i >> 6;
  Wt[(size_t)j*EE + k] = f2bf(W[i]);
}

// ---------------- Q/K projection GEMM (A-reuse, BK=32, 24 iters) ----------------
__global__ __launch_bounds__(256) void gemm_qk_k(const u16* __restrict__ Xh, const u16* __restrict__ Xl,
                                                 const u16* __restrict__ BT1,
                                                 u16* __restrict__ Qh, u16* __restrict__ Ql,
                                                 u16* __restrict__ Kh, u16* __restrict__ Kl){
  __shared__ u16 lds[2][4][4096];                // [buf][Xh,Xl,Wh,Wl][128*32] = 64 KB
  const int flat = blockIdx.x;                   // 1536 = 8 XCD * 192
  const int swz = (flat & 7)*192 + (flat >> 3);  // XCD-chunked, bc fastest (A-panel L2 reuse)
  const int rt = swz / 12, bc = swz - rt*12;
  const int row0 = rt*128, col0 = bc*128;
  const int tid = threadIdx.x;
  const int w = tid >> 6, l = tid & 63, lr = l & 15, lg = l >> 4;
  const int wr = w >> 1, wc = w & 1;
  const int sr = l >> 2, sce = (l & 3)*8;        // staging: 16 rows/wave-round, 32-col rows

  f32x4 acc[4][4];
  #pragma unroll
  for (int m=0;m<4;++m)
    #pragma unroll
    for (int n=0;n<4;++n) acc[m][n] = f32x4{0.f,0.f,0.f,0.f};

  auto stage = [&](int buf, int kt){
    const int e0 = kt*32;
    #pragma unroll
    for (int j=0;j<2;++j){
      const int r = w*32 + j*16;                 // wave-round row base
      const int gr = r + sr;                     // this lane's row
      u16* dst0 = &lds[buf][0][r*32];
      u16* dst1 = &lds[buf][1][r*32];
      u16* dst2 = &lds[buf][2][r*32];
      u16* dst3 = &lds[buf][3][r*32];
      stage16(Xh  + (size_t)(row0 + gr)*EE   + e0 + sce,        dst0);
      stage16(Xl  + (size_t)(row0 + gr)*EE   + e0 + sce,        dst1);
      stage16(BT1 + (size_t)(col0 + gr)*1536 + e0 + sce,        dst2);
      stage16(BT1 + (size_t)(col0 + gr)*1536 + 768 + e0 + sce,  dst3);
    }
  };

  stage(0, 0);
  __syncthreads();

  for (int kt=0; kt<24; ++kt){
    const int buf = kt & 1;
    if (kt + 1 < 24) stage(buf ^ 1, kt + 1);

    bf16x8 ah[4], al[4], bh[4], bl[4];
    #pragma unroll
    for (int m=0;m<4;++m){
      const int off = (wr*64 + m*16 + lr)*32 + lg*8;
      ah[m] = ld8(&lds[buf][0][off]);
      al[m] = ld8(&lds[buf][1][off]);
    }
    #pragma unroll
    for (int n=0;n<4;++n){
      const int off = (wc*64 + n*16 + lr)*32 + lg*8;
      bh[n] = ld8(&lds[buf][2][off]);
      bl[n] = ld8(&lds[buf][3][off]);
    }

    __builtin_amdgcn_s_setprio(1);
    #pragma unroll
    for (int m=0;m<4;++m)
      #pragma unroll
      for (int n=0;n<4;++n){
        acc[m][n] = mfma16(ah[m], bh[n], acc[m][n]);
        acc[m][n] = mfma16(ah[m], bl[n], acc[m][n]);
        acc[m][n] = mfma16(al[m], bh[n], acc[m][n]);
      }
    __builtin_amdgcn_s_setprio(0);

    __syncthreads();   // drains vmcnt (stage done) + all waves done reading buf
  }

  u16* Dh = wc ? Kh : Qh;
  u16* Dl = wc ? Kl : Ql;
  const size_t base = (size_t)bc*BN*DD;          // head = bc
  #pragma unroll
  for (int m=0;m<4;++m)
    #pragma unroll
    for (int n=0;n<4;++n)
      #pragma unroll
      for (int j=0;j<4;++j){
        int r = row0 + wr*64 + m*16 + lg*4 + j;
        int d = n*16 + lr;
        size_t o = base + (size_t)r*DD + d;
        u16 hi, lo; split2(acc[m][n][j], hi, lo);
        Dh[o] = hi; Dl[o] = lo;
      }
}

// ---------------- V projection GEMM (staged, 128x128 tile, BK=64) ----------------
__global__ __launch_bounds__(256) void gemm_v_k(const u16* __restrict__ Xh,
                                                const u16* __restrict__ BT,
                                                u16* __restrict__ Vt){
  __shared__ u16 lds[2][2][8192];                // [buf][A/B][128*64] = 64 KB
  const int flat = blockIdx.x;                   // 768 = 8 XCD * 96
  const int swz = (flat & 7)*96 + (flat >> 3);
  const int rt = swz / 6, bc = swz - rt*6;
  const int row0 = rt*128, col0 = bc*128;
  const int tid = threadIdx.x;
  const int w = tid >> 6, l = tid & 63, lr = l & 15, lg = l >> 4;
  const int wr = w >> 1, wc = w & 1;
  const int sr = l >> 3, sce = (l & 7)*8;

  f32x4 acc[4][4];
  #pragma unroll
  for (int m=0;m<4;++m)
    #pragma unroll
    for (int n=0;n<4;++n) acc[m][n] = f32x4{0.f,0.f,0.f,0.f};

  auto stage = [&](int buf, int kt){
    const int e0 = kt*64;
    const u16* ab = Xh + (size_t)row0*EE + e0 + sce;
    const u16* bb = BT + (size_t)col0*EE + e0 + sce;
    u16* la = &lds[buf][0][0];
    u16* lb = &lds[buf][1][0];
    #pragma unroll
    for (int j=0;j<4;++j){
      const int it = j*4 + w;
      stage16(ab + (size_t)(it*8 + sr)*EE, la + it*512);
      stage16(bb + (size_t)(it*8 + sr)*EE, lb + it*512);
    }
  };

  stage(0, 0);
  __syncthreads();

  for (int kt=0; kt<12; ++kt){
    const int buf = kt & 1;
    if (kt + 1 < 12) stage(buf ^ 1, kt + 1);

    const u16* la = &lds[buf][0][0];
    const u16* lb = &lds[buf][1][0];
    bf16x8 af[4][2], bfr[4][2];
    #pragma unroll
    for (int m=0;m<4;++m)
      #pragma unroll
      for (int ks=0;ks<2;++ks)
        af[m][ks] = ld8(la + (wr*64 + m*16 + lr)*64 + ks*32 + lg*8);
    #pragma unroll
    for (int n=0;n<4;++n)
      #pragma unroll
      for (int ks=0;ks<2;++ks)
        bfr[n][ks] = ld8(lb + (wc*64 + n*16 + lr)*64 + ks*32 + lg*8);

    #pragma unroll
    for (int ks=0;ks<2;++ks)
      #pragma unroll
      for (int m=0;m<4;++m)
        #pragma unroll
        for (int n=0;n<4;++n)
          acc[m][n] = mfma16(af[m][ks], bfr[n][ks], acc[m][n]);

    __syncthreads();
  }

  #pragma unroll
  for (int m=0;m<4;++m)
    #pragma unroll
    for (int n=0;n<4;++n){
      int c = col0 + wc*64 + n*16 + lr;
      int hh = c >> 6, d = c & 63;
      int r = row0 + wr*64 + m*16 + lg*4;
      int b = r >> 10, nn = r & 1023;
      // pre-permuted kv offset: nn..nn+3 -> group base + ks*32 + lg'*8 + jh*4 .. +3
      int kvb = nn & ~63, kvL = nn & 63;
      int ks = kvL >> 5, rem = kvL & 31;
      int lgp = (rem >> 2) & 3, jh = rem >> 4;
      int off = kvb + ks*32 + lgp*8 + jh*4;
      ushort4 pk;
      pk.x = f2bf(acc[m][n][0]); pk.y = f2bf(acc[m][n][1]);
      pk.z = f2bf(acc[m][n][2]); pk.w = f2bf(acc[m][n][3]);
      *(ushort4*)(Vt + ((size_t)((hh*16 + b)*DD + d))*NN + off) = pk;
    }
}

// ---------------- flash attention: 8-wave blocks, 3-pass bf16 QK, LDS-staged K ----------------
// v_exp_f32 direct (fexp2): denormal-safe libm expansion removed; underflow->0 is correct here.
// 2x unrolled KV loop (static LDS buf per body) + hoisted V pointers (+=64/body).
__global__ __launch_bounds__(512) void flash_k(const u16* __restrict__ Qh, const u16* __restrict__ Ql,
                                               const u16* __restrict__ Kh, const u16* __restrict__ Kl,
                                               const u16* __restrict__ Vt, u16* __restrict__ Cc){
  __shared__ u16 kbuf[2][2][4096];                 // [buf][hi/lo][64*64] = 32 KB
  const int flat = blockIdx.x;                     // 768 = 8 XCD * 96
  const int swz = (flat & 7)*96 + (flat >> 3);     // XCD chunking: all blocks of a (b,h) share L2
  const int qb = swz & 3, bh = swz >> 2;
  const int h = bh % 12, b = bh / 12;
  const int l = threadIdx.x & 63, w = threadIdx.x >> 6, lr = l & 15, lg = l >> 4;
  const size_t hb = (size_t)h*BN*DD + (size_t)b*NN*DD;
  const int q0 = qb*256 + w*32;

  const int srow = l >> 3;
  const int scol = 8*((l & 7) ^ srow);

  auto stage = [&](int buf, int t){
    const int kv0 = t*64;
    #pragma unroll
    for (int j=0;j<2;++j){
      const int c = w*2 + j;                       // 16 chunks over 8 waves: 0-7 Kh, 8-15 Kl
      const u16* src = (c < 8) ? Kh : Kl;
      const int cr = (c & 7)*8;
      stage16(src + hb + (size_t)(kv0 + cr + srow)*DD + scol,
              &kbuf[buf][c >> 3][(c & 7)*512]);
    }
  };

  bf16x8 qfh[2][2], qfl[2][2];
  #pragma unroll
  for (int qf=0;qf<2;++qf)
    #pragma unroll
    for (int ks=0;ks<2;++ks){
      size_t o = hb + (size_t)(q0 + qf*16 + lr)*DD + ks*32 + lg*8;
      qfh[qf][ks] = ld8(Qh + o);
      qfl[qf][ks] = ld8(Ql + o);
    }

  // hoisted V pointers (pre-permuted Vt): advance +64 elems per KV tile
  const u16* vp[4];
  #pragma unroll
  for (int df=0;df<4;++df)
    vp[df] = Vt + ((size_t)((h*16 + b)*DD + df*16 + lr))*NN + lg*8;

  f32x4 acc[2][4];                 // [qf][df] : O^T frags (row=d, col=q)
  float mr[2] = {-1e30f,-1e30f}, ls[2] = {0.f,0.f};   // ls = per-lane partial
  #pragma unroll
  for (int qf=0;qf<2;++qf)
    #pragma unroll
    for (int df=0;df<4;++df) acc[qf][df] = f32x4{0.f,0.f,0.f,0.f};

  stage(0, 0);
  __syncthreads();

  auto body = [&](int t, int buf){
    // V^T A-frags first (oldest vmem ops); single dwordx4 + offset:64 pair per df
    bf16x8 va[4][2];
    #pragma unroll
    for (int df=0;df<4;++df){
      va[df][0] = ld8(vp[df]);
      va[df][1] = ld8(vp[df] + 32);
      vp[df] += 64;
    }

    if (t + 1 < 16) stage(buf ^ 1, t + 1);         // prefetch next K tile

    f32x4 s[2][4];                 // [qf][kf]
    #pragma unroll
    for (int qf=0;qf<2;++qf)
      #pragma unroll
      for (int kf=0;kf<4;++kf) s[qf][kf] = f32x4{0.f,0.f,0.f,0.f};

    const char* kb = (const char*)&kbuf[buf][0][0];
    #pragma unroll
    for (int ks=0;ks<2;++ks){
      bf16x8 kh[4], kl2[4];
      #pragma unroll
      for (int kf=0;kf<4;++kf){
        const int r = kf*16 + lr;
        const int sw = (ks*64 + lg*16) ^ ((lr & 7) << 4);
        kh[kf]  = *(const bf16x8*)(kb + r*128 + sw);
        kl2[kf] = *(const bf16x8*)(kb + 8192 + r*128 + sw);
      }
      __builtin_amdgcn_s_setprio(1);
      #pragma unroll
      for (int qf=0;qf<2;++qf)
        #pragma unroll
        for (int kf=0;kf<4;++kf){
          s[qf][kf] = mfma16(kh[kf],  qfh[qf][ks], s[qf][kf]);
          s[qf][kf] = mfma16(kl2[kf], qfh[qf][ks], s[qf][kf]);
          s[qf][kf] = mfma16(kh[kf],  qfl[qf][ks], s[qf][kf]);
        }
      __builtin_amdgcn_s_setprio(0);
    }

    // softmax (exp2 domain; lazy group rescale; per lane: 2 q-rows)
    bf16x8 pb[2][2];
    #pragma unroll
    for (int qf=0;qf<2;++qf){
      float a0 = fmaxf(fmaxf(s[qf][0][0], s[qf][0][1]), fmaxf(s[qf][0][2], s[qf][0][3]));
      float a1 = fmaxf(fmaxf(s[qf][1][0], s[qf][1][1]), fmaxf(s[qf][1][2], s[qf][1][3]));
      float a2 = fmaxf(fmaxf(s[qf][2][0], s[qf][2][1]), fmaxf(s[qf][2][2], s[qf][2][3]));
      float a3 = fmaxf(fmaxf(s[qf][3][0], s[qf][3][1]), fmaxf(s[qf][3][2], s[qf][3][3]));
      float pm = fmaxf(fmaxf(a0, a1), fmaxf(a2, a3));
      if (__any(pm > mr[qf] + 8.f)){               // max growth -> rescale
        pm = fmaxf(pm, __shfl_xor(pm, 16, 64));
        pm = fmaxf(pm, __shfl_xor(pm, 32, 64));
        const float mn = fmaxf(mr[qf], pm);
        const float fs = fexp2(mr[qf] - mn);
        mr[qf] = mn;
        ls[qf] *= fs;
        #pragma unroll
        for (int df=0;df<4;++df)
          #pragma unroll
          for (int r=0;r<4;++r) acc[qf][df][r] *= fs;
      }
      float rs = 0.f;
      #pragma unroll
      for (int kf=0;kf<4;++kf)
        #pragma unroll
        for (int r=0;r<4;++r){
          float e = fexp2(s[qf][kf][r] - mr[qf]);  // bounded by 2^8; underflow->0 fine
          s[qf][kf][r] = e;
          rs += e;
        }
      ls[qf] += rs;
      #pragma unroll
      for (int ks=0;ks<2;++ks){
        U8 pu;
        pu.w[0] = pk2(s[qf][2*ks][0],   s[qf][2*ks][1]);
        pu.w[1] = pk2(s[qf][2*ks][2],   s[qf][2*ks][3]);
        pu.w[2] = pk2(s[qf][2*ks+1][0], s[qf][2*ks+1][1]);
        pu.w[3] = pk2(s[qf][2*ks+1][2], s[qf][2*ks+1][3]);
        pb[qf][ks] = pu.v;
      }
    }

    // PV: O^T += V^T * P  (bf16)
    __builtin_amdgcn_s_setprio(1);
    #pragma unroll
    for (int ks=0;ks<2;++ks)
      #pragma unroll
      for (int qf=0;qf<2;++qf)
        #pragma unroll
        for (int df=0;df<4;++df)
          acc[qf][df] = mfma16(va[df][ks], pb[qf][ks], acc[qf][df]);
    __builtin_amdgcn_s_setprio(0);

    __syncthreads();
  };

  for (int tt=0; tt<8; ++tt){
    body(tt*2,     0);
    body(tt*2 + 1, 1);
  }

  #pragma unroll
  for (int qf=0;qf<2;++qf){
    float t1 = ls[qf] + __shfl_xor(ls[qf], 16, 64);
    t1 += __shfl_xor(t1, 32, 64);
    const float inv = 1.0f / t1;
    #pragma unroll
    for (int df=0;df<4;++df){
      ushort4 o4;
      o4.x = f2bf(acc[qf][df][0]*inv);
      o4.y = f2bf(acc[qf][df][1]*inv);
      o4.z = f2bf(acc[qf][df][2]*inv);
      o4.w = f2bf(acc[qf][df][3]*inv);
      *(ushort4*)(Cc + (size_t)(b*NN + q0 + qf*16 + lr)*EE + h*DD + df*16 + lg*4) = o4;
    }
  }
}

// ---------------- output projection (staged, 64-row tiles, BK=64) ----------------
__global__ __launch_bounds__(256) void gemm_o_k(const u16* __restrict__ Cc, const u16* __restrict__ Wot,
                                                float* __restrict__ out){
  __shared__ u16 lds[2][2][4096];                // [buf][A/B][64*64] = 32 KB
  const int rt = blockIdx.x;                     // 256 blocks x 64 rows
  const int tid = threadIdx.x;
  const int w = tid >> 6, l = tid & 63, lr = l & 15, lg = l >> 4;
  const int row0 = rt*64;
  const int sr = l >> 3, sce = (l & 7)*8;        // staging: 8 rows/wave-round, 64-col rows

  f32x4 acc[4];
  #pragma unroll
  for (int n=0;n<4;++n) acc[n] = f32x4{0.f,0.f,0.f,0.f};

  auto stage = [&](int buf, int kt){
    const int e0 = kt*64;
    #pragma unroll
    for (int j=0;j<2;++j){
      const int r = w*16 + j*8;                  // wave-round row base
      stage16(Cc  + (size_t)(row0 + r + sr)*EE + e0 + sce, &lds[buf][0][r*64]);
      stage16(Wot + (size_t)(r + sr)*EE        + e0 + sce, &lds[buf][1][r*64]);
    }
  };

  stage(0, 0);
  __syncthreads();

  for (int kt=0; kt<12; ++kt){
    const int buf = kt & 1;
    if (kt + 1 < 12) stage(buf ^ 1, kt + 1);

    bf16x8 a[2], bb[4][2];
    #pragma unroll
    for (int ks=0;ks<2;++ks)
      a[ks] = ld8(&lds[buf][0][(w*16 + lr)*64 + ks*32 + lg*8]);
    #pragma unroll
    for (int nf=0;nf<4;++nf)
      #pragma unroll
      for (int ks=0;ks<2;++ks)
        bb[nf][ks] = ld8(&lds[buf][1][(nf*16 + lr)*64 + ks*32 + lg*8]);

    #pragma unroll
    for (int ks=0;ks<2;++ks)
      #pragma unroll
      for (int nf=0;nf<4;++nf)
        acc[nf] = mfma16(a[ks], bb[nf][ks], acc[nf]);

    __syncthreads();
  }

  #pragma unroll
  for (int nf=0;nf<4;++nf)
    #pragma unroll
    for (int j=0;j<4;++j)
      out[(size_t)(row0 + w*16 + lg*4 + j)*DD + nf*16 + lr] = acc[nf][j];
}

// ---------------- launch ----------------
extern "C" void kernel_launch(void* const* d_in, const int* in_sizes, int n_in,
                              void* d_out, int out_size, void* d_ws, size_t ws_size,
                              hipStream_t stream) {
  const float* x  = (const float*)d_in[0];
  const float* Wq = (const float*)d_in[1];
  const float* Wk = (const float*)d_in[2];
  const float* Wv = (const float*)d_in[3];
  const float* Wo = (const float*)d_in[4];
  float* out = (float*)d_out;

  u16* ws = (u16*)d_ws;
  const size_t SB = (size_t)12582912;   // 16384*768
  u16* Xh  = ws;
  u16* Xl  = Xh + SB;
  u16* Qh  = Xl + SB;
  u16* Ql  = Qh + SB;
  u16* Kh  = Ql + SB;
  u16* Kl  = Kh + SB;
  u16* Vt  = Kl + SB;
  u16* Cc  = Vt + SB;
  u16* Wot = Cc + SB;
  // BT1/BT2 alias into Cc: written by packs, read by GEMMs, then Cc is fully
  // overwritten by flash_k before gemm_o_k reads it (in-stream ordering).
  u16* BT1 = Cc;                        // 1536*1536 = 2359296 elems
  u16* BT2 = Cc + 2359296;              // 768*768   =  589824 elems

  split_x_k <<<12288, 256, 0, stream>>>(x, Xh, Xl);
  pack_bt1_k<<<9216,  256, 0, stream>>>(Wq, Wk, BT1);
  pack_bt2_k<<<2304,  256, 0, stream>>>(Wv, BT2);
  pack_wo_k <<<192,   256, 0, stream>>>(Wo, Wot);

  gemm_qk_k<<<1536, 256, 0, stream>>>(Xh, Xl, BT1, Qh, Ql, Kh, Kl);
  gemm_v_k <<<768,  256, 0, stream>>>(Xh, BT2, Vt);
  flash_k  <<<768,  512, 0, stream>>>(Qh, Ql, Kh, Kl, Vt, Cc);
  gemm_o_k <<<256,  256, 0, stream>>>(Cc, Wot, out);
}

// Round 11
// 299.175 us; speedup vs baseline: 1.6853x; 1.0427x over previous
//
#include <hip/hip_runtime.h>
#include <hip/hip_bf16.h>

typedef unsigned short u16;
typedef unsigned int u32;
typedef __attribute__((ext_vector_type(8))) short bf16x8;   // 8x16-bit in 4 VGPRs
typedef __attribute__((ext_vector_type(4))) float f32x4;

#define DEV static __device__ __forceinline__

#define BB 16
#define NN 1024
#define EE 768
#define HH 12
#define DD 64
#define BN (BB*NN)   // 16384

DEV u16 f2bf(float f){ __hip_bfloat16 h = __float2bfloat16(f); u16 u; __builtin_memcpy(&u, &h, 2); return u; }
DEV float bf2f(u16 u){ __hip_bfloat16 h; __builtin_memcpy(&h, &u, 2); return __bfloat162float(h); }
DEV void split2(float v, u16& hi, u16& lo){ hi = f2bf(v); lo = f2bf(v - bf2f(hi)); }
DEV bf16x8 ld8(const u16* p){ return *(const bf16x8*)p; }
DEV f32x4 mfma16(bf16x8 a, bf16x8 b, f32x4 c){ return __builtin_amdgcn_mfma_f32_16x16x32_bf16(a, b, c, 0, 0, 0); }
DEV float fexp2(float x){ return __builtin_amdgcn_exp2f(x); }   // raw v_exp_f32; underflow->0 is wanted
DEV u32 pk2(float a, float b){                       // 2xf32 -> packed 2xbf16 (v_cvt_pk_bf16_f32)
  float2 f{a, b};
  __hip_bfloat162 t = __float22bfloat162_rn(f);
  u32 r; __builtin_memcpy(&r, &t, 4); return r;
}

union U8 { bf16x8 v; u16 e[8]; ushort4 q[2]; u32 w[4]; };

// async global->LDS, 16B per lane. LDS dst must be wave-uniform; HW adds lane*16.
DEV void stage16(const u16* g, u16* l){
  __builtin_amdgcn_global_load_lds((const __attribute__((address_space(1))) void*)g,
                                   (__attribute__((address_space(3))) void*)l,
                                   16, 0, 0);
}

// ---------------- uber prep kernel (split_x + pack_bt1 + pack_bt2 + pack_wo) ----------------
__global__ __launch_bounds__(256) void prep_k(const float* __restrict__ x,
                                              const float* __restrict__ Wq,
                                              const float* __restrict__ Wk,
                                              const float* __restrict__ Wv,
                                              const float* __restrict__ Wo,
                                              u16* __restrict__ Xh, u16* __restrict__ Xl,
                                              u16* __restrict__ BT1, u16* __restrict__ BT2,
                                              u16* __restrict__ Wot){
  const int bid = blockIdx.x, tid = threadIdx.x;
  if (bid < 12288){
    // split x (fp32) -> bf16 hi/lo, 4 elems/thread
    int i = bid*256 + tid;                       // < 3145728
    const float4 v = ((const float4*)x)[i];
    ushort4 h, l;
    split2(v.x, h.x, l.x);
    split2(v.y, h.y, l.y);
    split2(v.z, h.z, l.z);
    split2(v.w, h.w, l.w);
    ((ushort4*)Xh)[i] = h;
    ((ushort4*)Xl)[i] = l;
  } else if (bid < 21504){
    // BT1[1536][1536]: row c -> h=c>>7, g=(c>>6)&1 (0=Q,1=K), d=c&63; col k<768 hi / >=768 lo.
    // Q scale folds 1/sqrt(D) and log2(e) (exp2-domain softmax).
    int i = (bid - 12288)*256 + tid;             // < 2359296
    int c = i / 1536, k = i - c*1536;
    int seg = (k >= 768);
    int e = k - seg*768;
    int h = c >> 7, g = (c >> 6) & 1, d = c & 63;
    const float* W = g ? Wk : Wq;
    float v = W[((size_t)h*EE + e)*DD + d] * (g ? 1.0f : 0.125f*1.4426950408889634f);
    u16 hi, lo; split2(v, hi, lo);
    BT1[i] = seg ? lo : hi;
  } else if (bid < 23808){
    // BT2[768][768]: c -> h=c>>6, d=c&63; k=e. Plain bf16.
    int i = (bid - 21504)*256 + tid;             // < 589824
    int c = i / 768, e = i - c*768;
    int h = c >> 6, d = c & 63;
    BT2[i] = f2bf(Wv[((size_t)h*EE + e)*DD + d]);
  } else {
    // Wot[D][H*D] bf16
    int i = (bid - 23808)*256 + tid;             // < 49152
    int j = i & 63, k = i >> 6;
    Wot[(size_t)j*EE + k] = f2bf(Wo[i]);
  }
}

// ---------------- Q/K projection (A-reuse, BK=32, 24 iters) — device body ----------------
DEV void do_qk(int flat, int tid, u16* lds,
               const u16* __restrict__ Xh, const u16* __restrict__ Xl,
               const u16* __restrict__ BT1,
               u16* __restrict__ Qh, u16* __restrict__ Ql,
               u16* __restrict__ Kh, u16* __restrict__ Kl){
  // lds layout: [buf][Xh,Xl,Wh,Wl][128*32]  (8 panels of 4096 u16 = 64 KB)
  const int swz = (flat & 7)*192 + (flat >> 3);  // XCD-chunked, bc fastest
  const int rt = swz / 12, bc = swz - rt*12;
  const int row0 = rt*128, col0 = bc*128;
  const int w = tid >> 6, l = tid & 63, lr = l & 15, lg = l >> 4;
  const int wr = w >> 1, wc = w & 1;
  const int sr = l >> 2, sce = (l & 3)*8;

  f32x4 acc[4][4];
  #pragma unroll
  for (int m=0;m<4;++m)
    #pragma unroll
    for (int n=0;n<4;++n) acc[m][n] = f32x4{0.f,0.f,0.f,0.f};

  auto stage = [&](int buf, int kt){
    const int e0 = kt*32;
    #pragma unroll
    for (int j=0;j<2;++j){
      const int r = w*32 + j*16;
      const int gr = r + sr;
      u16* base = lds + buf*16384 + r*32;
      stage16(Xh  + (size_t)(row0 + gr)*EE   + e0 + sce,        base);
      stage16(Xl  + (size_t)(row0 + gr)*EE   + e0 + sce,        base + 4096);
      stage16(BT1 + (size_t)(col0 + gr)*1536 + e0 + sce,        base + 8192);
      stage16(BT1 + (size_t)(col0 + gr)*1536 + 768 + e0 + sce,  base + 12288);
    }
  };

  stage(0, 0);
  __syncthreads();

  for (int kt=0; kt<24; ++kt){
    const int buf = kt & 1;
    if (kt + 1 < 24) stage(buf ^ 1, kt + 1);

    bf16x8 ah[4], al[4], bh[4], bl[4];
    #pragma unroll
    for (int m=0;m<4;++m){
      const int off = buf*16384 + (wr*64 + m*16 + lr)*32 + lg*8;
      ah[m] = ld8(lds + off);
      al[m] = ld8(lds + off + 4096);
    }
    #pragma unroll
    for (int n=0;n<4;++n){
      const int off = buf*16384 + (wc*64 + n*16 + lr)*32 + lg*8;
      bh[n] = ld8(lds + off + 8192);
      bl[n] = ld8(lds + off + 12288);
    }

    __builtin_amdgcn_s_setprio(1);
    #pragma unroll
    for (int m=0;m<4;++m)
      #pragma unroll
      for (int n=0;n<4;++n){
        acc[m][n] = mfma16(ah[m], bh[n], acc[m][n]);
        acc[m][n] = mfma16(ah[m], bl[n], acc[m][n]);
        acc[m][n] = mfma16(al[m], bh[n], acc[m][n]);
      }
    __builtin_amdgcn_s_setprio(0);

    __syncthreads();
  }

  u16* Dh = wc ? Kh : Qh;
  u16* Dl = wc ? Kl : Ql;
  const size_t base = (size_t)bc*BN*DD;          // head = bc
  #pragma unroll
  for (int m=0;m<4;++m)
    #pragma unroll
    for (int n=0;n<4;++n)
      #pragma unroll
      for (int j=0;j<4;++j){
        int r = row0 + wr*64 + m*16 + lg*4 + j;
        int d = n*16 + lr;
        size_t o = base + (size_t)r*DD + d;
        u16 hi, lo; split2(acc[m][n][j], hi, lo);
        Dh[o] = hi; Dl[o] = lo;
      }
}

// ---------------- V projection (staged, 128x128, BK=64) — device body ----------------
DEV void do_v(int flat, int tid, u16* lds,
              const u16* __restrict__ Xh, const u16* __restrict__ BT,
              u16* __restrict__ Vt){
  // lds layout: [buf][A/B][128*64]  (4 panels of 8192 u16 = 64 KB)
  const int swz = (flat & 7)*96 + (flat >> 3);
  const int rt = swz / 6, bc = swz - rt*6;
  const int row0 = rt*128, col0 = bc*128;
  const int w = tid >> 6, l = tid & 63, lr = l & 15, lg = l >> 4;
  const int wr = w >> 1, wc = w & 1;
  const int sr = l >> 3, sce = (l & 7)*8;

  f32x4 acc[4][4];
  #pragma unroll
  for (int m=0;m<4;++m)
    #pragma unroll
    for (int n=0;n<4;++n) acc[m][n] = f32x4{0.f,0.f,0.f,0.f};

  auto stage = [&](int buf, int kt){
    const int e0 = kt*64;
    const u16* ab = Xh + (size_t)row0*EE + e0 + sce;
    const u16* bb = BT + (size_t)col0*EE + e0 + sce;
    u16* la = lds + buf*16384;
    u16* lb = la + 8192;
    #pragma unroll
    for (int j=0;j<4;++j){
      const int it = j*4 + w;
      stage16(ab + (size_t)(it*8 + sr)*EE, la + it*512);
      stage16(bb + (size_t)(it*8 + sr)*EE, lb + it*512);
    }
  };

  stage(0, 0);
  __syncthreads();

  for (int kt=0; kt<12; ++kt){
    const int buf = kt & 1;
    if (kt + 1 < 12) stage(buf ^ 1, kt + 1);

    const u16* la = lds + buf*16384;
    const u16* lb = la + 8192;
    bf16x8 af[4][2], bfr[4][2];
    #pragma unroll
    for (int m=0;m<4;++m)
      #pragma unroll
      for (int ks=0;ks<2;++ks)
        af[m][ks] = ld8(la + (wr*64 + m*16 + lr)*64 + ks*32 + lg*8);
    #pragma unroll
    for (int n=0;n<4;++n)
      #pragma unroll
      for (int ks=0;ks<2;++ks)
        bfr[n][ks] = ld8(lb + (wc*64 + n*16 + lr)*64 + ks*32 + lg*8);

    #pragma unroll
    for (int ks=0;ks<2;++ks)
      #pragma unroll
      for (int m=0;m<4;++m)
        #pragma unroll
        for (int n=0;n<4;++n)
          acc[m][n] = mfma16(af[m][ks], bfr[n][ks], acc[m][n]);

    __syncthreads();
  }

  #pragma unroll
  for (int m=0;m<4;++m)
    #pragma unroll
    for (int n=0;n<4;++n){
      int c = col0 + wc*64 + n*16 + lr;
      int hh = c >> 6, d = c & 63;
      int r = row0 + wr*64 + m*16 + lg*4;
      int b = r >> 10, nn = r & 1023;
      // pre-permuted kv offset for flash PV frags
      int kvb = nn & ~63, kvL = nn & 63;
      int ks = kvL >> 5, rem = kvL & 31;
      int lgp = (rem >> 2) & 3, jh = rem >> 4;
      int off = kvb + ks*32 + lgp*8 + jh*4;
      ushort4 pk;
      pk.x = f2bf(acc[m][n][0]); pk.y = f2bf(acc[m][n][1]);
      pk.z = f2bf(acc[m][n][2]); pk.w = f2bf(acc[m][n][3]);
      *(ushort4*)(Vt + ((size_t)((hh*16 + b)*DD + d))*NN + off) = pk;
    }
}

// ---------------- uber projection kernel (QK blocks 0..1535, V blocks 1536..2303) ----------------
__global__ __launch_bounds__(256) void proj_k(const u16* __restrict__ Xh, const u16* __restrict__ Xl,
                                              const u16* __restrict__ BT1, const u16* __restrict__ BT2,
                                              u16* __restrict__ Qh, u16* __restrict__ Ql,
                                              u16* __restrict__ Kh, u16* __restrict__ Kl,
                                              u16* __restrict__ Vt){
  __shared__ u16 lds[32768];                     // 64 KB, shared by both bodies
  if (blockIdx.x < 1536)
    do_qk(blockIdx.x, threadIdx.x, lds, Xh, Xl, BT1, Qh, Ql, Kh, Kl);
  else
    do_v(blockIdx.x - 1536, threadIdx.x, lds, Xh, BT2, Vt);
}

// ---------------- flash attention: 8-wave blocks, quad-buffered K, barrier per 2 KV tiles ----------------
__global__ __launch_bounds__(512) void flash_k(const u16* __restrict__ Qh, const u16* __restrict__ Ql,
                                               const u16* __restrict__ Kh, const u16* __restrict__ Kl,
                                               const u16* __restrict__ Vt, u16* __restrict__ Cc){
  __shared__ u16 kbuf[4][2][4096];                 // [tilebuf][hi/lo][64*64] = 64 KB
  const int flat = blockIdx.x;                     // 768 = 8 XCD * 96
  const int swz = (flat & 7)*96 + (flat >> 3);     // XCD chunking: all blocks of a (b,h) share L2
  const int qb = swz & 3, bh = swz >> 2;
  const int h = bh % 12, b = bh / 12;
  const int l = threadIdx.x & 63, w = threadIdx.x >> 6, lr = l & 15, lg = l >> 4;
  const size_t hb = (size_t)h*BN*DD + (size_t)b*NN*DD;
  const int q0 = qb*256 + w*32;

  const int srow = l >> 3;
  const int scol = 8*((l & 7) ^ srow);

  auto stage = [&](int buf, int t){
    const int kv0 = t*64;
    #pragma unroll
    for (int j=0;j<2;++j){
      const int c = w*2 + j;                       // 16 chunks over 8 waves: 0-7 Kh, 8-15 Kl
      const u16* src = (c < 8) ? Kh : Kl;
      const int cr = (c & 7)*8;
      stage16(src + hb + (size_t)(kv0 + cr + srow)*DD + scol,
              &kbuf[buf][c >> 3][(c & 7)*512]);
    }
  };

  bf16x8 qfh[2][2], qfl[2][2];
  #pragma unroll
  for (int qf=0;qf<2;++qf)
    #pragma unroll
    for (int ks=0;ks<2;++ks){
      size_t o = hb + (size_t)(q0 + qf*16 + lr)*DD + ks*32 + lg*8;
      qfh[qf][ks] = ld8(Qh + o);
      qfl[qf][ks] = ld8(Ql + o);
    }

  // hoisted V pointers (pre-permuted Vt): advance +64 elems per KV tile
  const u16* vp[4];
  #pragma unroll
  for (int df=0;df<4;++df)
    vp[df] = Vt + ((size_t)((h*16 + b)*DD + df*16 + lr))*NN + lg*8;

  f32x4 acc[2][4];                 // [qf][df] : O^T frags (row=d, col=q)
  float mr[2] = {-1e30f,-1e30f}, ls[2] = {0.f,0.f};   // ls = per-lane partial
  #pragma unroll
  for (int qf=0;qf<2;++qf)
    #pragma unroll
    for (int df=0;df<4;++df) acc[qf][df] = f32x4{0.f,0.f,0.f,0.f};

  auto tb = [&](int buf){
    // V^T A-frags first (oldest vmem ops)
    bf16x8 va[4][2];
    #pragma unroll
    for (int df=0;df<4;++df){
      va[df][0] = ld8(vp[df]);
      va[df][1] = ld8(vp[df] + 32);
      vp[df] += 64;
    }

    f32x4 s[2][4];                 // [qf][kf]
    #pragma unroll
    for (int qf=0;qf<2;++qf)
      #pragma unroll
      for (int kf=0;kf<4;++kf) s[qf][kf] = f32x4{0.f,0.f,0.f,0.f};

    const char* kb = (const char*)&kbuf[buf][0][0];
    #pragma unroll
    for (int ks=0;ks<2;++ks){
      bf16x8 kh[4], kl2[4];
      #pragma unroll
      for (int kf=0;kf<4;++kf){
        const int r = kf*16 + lr;
        const int sw = (ks*64 + lg*16) ^ ((lr & 7) << 4);
        kh[kf]  = *(const bf16x8*)(kb + r*128 + sw);
        kl2[kf] = *(const bf16x8*)(kb + 8192 + r*128 + sw);
      }
      __builtin_amdgcn_s_setprio(1);
      #pragma unroll
      for (int qf=0;qf<2;++qf)
        #pragma unroll
        for (int kf=0;kf<4;++kf){
          s[qf][kf] = mfma16(kh[kf],  qfh[qf][ks], s[qf][kf]);
          s[qf][kf] = mfma16(kl2[kf], qfh[qf][ks], s[qf][kf]);
          s[qf][kf] = mfma16(kh[kf],  qfl[qf][ks], s[qf][kf]);
        }
      __builtin_amdgcn_s_setprio(0);
    }

    // softmax (exp2 domain; lazy group rescale; per lane: 2 q-rows)
    bf16x8 pb[2][2];
    #pragma unroll
    for (int qf=0;qf<2;++qf){
      float a0 = fmaxf(fmaxf(s[qf][0][0], s[qf][0][1]), fmaxf(s[qf][0][2], s[qf][0][3]));
      float a1 = fmaxf(fmaxf(s[qf][1][0], s[qf][1][1]), fmaxf(s[qf][1][2], s[qf][1][3]));
      float a2 = fmaxf(fmaxf(s[qf][2][0], s[qf][2][1]), fmaxf(s[qf][2][2], s[qf][2][3]));
      float a3 = fmaxf(fmaxf(s[qf][3][0], s[qf][3][1]), fmaxf(s[qf][3][2], s[qf][3][3]));
      float pm = fmaxf(fmaxf(a0, a1), fmaxf(a2, a3));
      if (__any(pm > mr[qf] + 8.f)){               // max growth -> rescale
        pm = fmaxf(pm, __shfl_xor(pm, 16, 64));
        pm = fmaxf(pm, __shfl_xor(pm, 32, 64));
        const float mn = fmaxf(mr[qf], pm);
        const float fs = fexp2(mr[qf] - mn);
        mr[qf] = mn;
        ls[qf] *= fs;
        #pragma unroll
        for (int df=0;df<4;++df)
          #pragma unroll
          for (int r=0;r<4;++r) acc[qf][df][r] *= fs;
      }
      float rs = 0.f;
      #pragma unroll
      for (int kf=0;kf<4;++kf)
        #pragma unroll
        for (int r=0;r<4;++r){
          float e = fexp2(s[qf][kf][r] - mr[qf]);  // bounded by 2^8; underflow->0 fine
          s[qf][kf][r] = e;
          rs += e;
        }
      ls[qf] += rs;
      #pragma unroll
      for (int ks=0;ks<2;++ks){
        U8 pu;
        pu.w[0] = pk2(s[qf][2*ks][0],   s[qf][2*ks][1]);
        pu.w[1] = pk2(s[qf][2*ks][2],   s[qf][2*ks][3]);
        pu.w[2] = pk2(s[qf][2*ks+1][0], s[qf][2*ks+1][1]);
        pu.w[3] = pk2(s[qf][2*ks+1][2], s[qf][2*ks+1][3]);
        pb[qf][ks] = pu.v;
      }
    }

    // PV: O^T += V^T * P  (bf16)
    __builtin_amdgcn_s_setprio(1);
    #pragma unroll
    for (int ks=0;ks<2;++ks)
      #pragma unroll
      for (int qf=0;qf<2;++qf)
        #pragma unroll
        for (int df=0;df<4;++df)
          acc[qf][df] = mfma16(va[df][ks], pb[qf][ks], acc[qf][df]);
    __builtin_amdgcn_s_setprio(0);
  };

  stage(0, 0);
  stage(1, 1);
  __syncthreads();

  for (int ss=0; ss<8; ++ss){
    const int cur = (ss & 1) << 1;                 // 0 or 2
    if (ss < 7){
      stage(cur ^ 2,       2*ss + 2);              // prefetch next tile pair
      stage((cur ^ 2) + 1, 2*ss + 3);
    }
    tb(cur);                                       // tile 2ss
    tb(cur + 1);                                   // tile 2ss+1
    __syncthreads();                               // one barrier per 2 tiles
  }

  #pragma unroll
  for (int qf=0;qf<2;++qf){
    float t1 = ls[qf] + __shfl_xor(ls[qf], 16, 64);
    t1 += __shfl_xor(t1, 32, 64);
    const float inv = 1.0f / t1;
    #pragma unroll
    for (int df=0;df<4;++df){
      ushort4 o4;
      o4.x = f2bf(acc[qf][df][0]*inv);
      o4.y = f2bf(acc[qf][df][1]*inv);
      o4.z = f2bf(acc[qf][df][2]*inv);
      o4.w = f2bf(acc[qf][df][3]*inv);
      *(ushort4*)(Cc + (size_t)(b*NN + q0 + qf*16 + lr)*EE + h*DD + df*16 + lg*4) = o4;
    }
  }
}

// ---------------- output projection (staged, 64-row tiles, BK=64) ----------------
__global__ __launch_bounds__(256) void gemm_o_k(const u16* __restrict__ Cc, const u16* __restrict__ Wot,
                                                float* __restrict__ out){
  __shared__ u16 lds[2][2][4096];                // [buf][A/B][64*64] = 32 KB
  const int rt = blockIdx.x;                     // 256 blocks x 64 rows
  const int tid = threadIdx.x;
  const int w = tid >> 6, l = tid & 63, lr = l & 15, lg = l >> 4;
  const int row0 = rt*64;
  const int sr = l >> 3, sce = (l & 7)*8;

  f32x4 acc[4];
  #pragma unroll
  for (int n=0;n<4;++n) acc[n] = f32x4{0.f,0.f,0.f,0.f};

  auto stage = [&](int buf, int kt){
    const int e0 = kt*64;
    #pragma unroll
    for (int j=0;j<2;++j){
      const int r = w*16 + j*8;
      stage16(Cc  + (size_t)(row0 + r + sr)*EE + e0 + sce, &lds[buf][0][r*64]);
      stage16(Wot + (size_t)(r + sr)*EE        + e0 + sce, &lds[buf][1][r*64]);
    }
  };

  stage(0, 0);
  __syncthreads();

  for (int kt=0; kt<12; ++kt){
    const int buf = kt & 1;
    if (kt + 1 < 12) stage(buf ^ 1, kt + 1);

    bf16x8 a[2], bb[4][2];
    #pragma unroll
    for (int ks=0;ks<2;++ks)
      a[ks] = ld8(&lds[buf][0][(w*16 + lr)*64 + ks*32 + lg*8]);
    #pragma unroll
    for (int nf=0;nf<4;++nf)
      #pragma unroll
      for (int ks=0;ks<2;++ks)
        bb[nf][ks] = ld8(&lds[buf][1][(nf*16 + lr)*64 + ks*32 + lg*8]);

    #pragma unroll
    for (int ks=0;ks<2;++ks)
      #pragma unroll
      for (int nf=0;nf<4;++nf)
        acc[nf] = mfma16(a[ks], bb[nf][ks], acc[nf]);

    __syncthreads();
  }

  #pragma unroll
  for (int nf=0;nf<4;++nf)
    #pragma unroll
    for (int j=0;j<4;++j)
      out[(size_t)(row0 + w*16 + lg*4 + j)*DD + nf*16 + lr] = acc[nf][j];
}

// ---------------- launch ----------------
extern "C" void kernel_launch(void* const* d_in, const int* in_sizes, int n_in,
                              void* d_out, int out_size, void* d_ws, size_t ws_size,
                              hipStream_t stream) {
  const float* x  = (const float*)d_in[0];
  const float* Wq = (const float*)d_in[1];
  const float* Wk = (const float*)d_in[2];
  const float* Wv = (const float*)d_in[3];
  const float* Wo = (const float*)d_in[4];
  float* out = (float*)d_out;

  u16* ws = (u16*)d_ws;
  const size_t SB = (size_t)12582912;   // 16384*768
  u16* Xh  = ws;
  u16* Xl  = Xh + SB;
  u16* Qh  = Xl + SB;
  u16* Ql  = Qh + SB;
  u16* Kh  = Ql + SB;
  u16* Kl  = Kh + SB;
  u16* Vt  = Kl + SB;
  u16* Cc  = Vt + SB;
  u16* Wot = Cc + SB;
  // BT1/BT2 alias into Cc: written by prep, read by proj, then Cc is fully
  // overwritten by flash_k before gemm_o_k reads it (in-stream ordering).
  u16* BT1 = Cc;                        // 1536*1536 = 2359296 elems
  u16* BT2 = Cc + 2359296;              // 768*768   =  589824 elems

  prep_k<<<24000, 256, 0, stream>>>(x, Wq, Wk, Wv, Wo, Xh, Xl, BT1, BT2, Wot);
  proj_k<<<2304,  256, 0, stream>>>(Xh, Xl, BT1, BT2, Qh, Ql, Kh, Kl, Vt);
  flash_k<<<768,  512, 0, stream>>>(Qh, Ql, Kh, Kl, Vt, Cc);
  gemm_o_k<<<256, 256, 0, stream>>>(Cc, Wot, out);
}

// Round 12
// 294.265 us; speedup vs baseline: 1.7134x; 1.0167x over previous
//
#include <hip/hip_runtime.h>
#include <hip/hip_bf16.h>

typedef unsigned short u16;
typedef unsigned int u32;
typedef __attribute__((ext_vector_type(8))) short bf16x8;   // 8x16-bit in 4 VGPRs
typedef __attribute__((ext_vector_type(4))) float f32x4;

#define DEV static __device__ __forceinline__

#define BB 16
#define NN 1024
#define EE 768
#define HH 12
#define DD 64
#define BN (BB*NN)   // 16384

DEV u16 f2bf(float f){ __hip_bfloat16 h = __float2bfloat16(f); u16 u; __builtin_memcpy(&u, &h, 2); return u; }
DEV float bf2f(u16 u){ __hip_bfloat16 h; __builtin_memcpy(&h, &u, 2); return __bfloat162float(h); }
DEV void split2(float v, u16& hi, u16& lo){ hi = f2bf(v); lo = f2bf(v - bf2f(hi)); }
DEV bf16x8 ld8(const u16* p){ return *(const bf16x8*)p; }
DEV f32x4 mfma16(bf16x8 a, bf16x8 b, f32x4 c){ return __builtin_amdgcn_mfma_f32_16x16x32_bf16(a, b, c, 0, 0, 0); }
DEV float fexp2(float x){ return __builtin_amdgcn_exp2f(x); }   // raw v_exp_f32; underflow->0 is wanted
DEV u32 pk2(float a, float b){                       // 2xf32 -> packed 2xbf16 (v_cvt_pk_bf16_f32)
  float2 f{a, b};
  __hip_bfloat162 t = __float22bfloat162_rn(f);
  u32 r; __builtin_memcpy(&r, &t, 4); return r;
}

union U8 { bf16x8 v; u16 e[8]; ushort4 q[2]; u32 w[4]; };

// async global->LDS, 16B per lane. LDS dst must be wave-uniform; HW adds lane*16.
DEV void stage16(const u16* g, u16* l){
  __builtin_amdgcn_global_load_lds((const __attribute__((address_space(1))) void*)g,
                                   (__attribute__((address_space(3))) void*)l,
                                   16, 0, 0);
}

// ---------------- uber prep kernel (split_x + pack_bt1 + pack_bt2 + pack_wo) ----------------
__global__ __launch_bounds__(256) void prep_k(const float* __restrict__ x,
                                              const float* __restrict__ Wq,
                                              const float* __restrict__ Wk,
                                              const float* __restrict__ Wv,
                                              const float* __restrict__ Wo,
                                              u16* __restrict__ Xh, u16* __restrict__ Xl,
                                              u16* __restrict__ BT1, u16* __restrict__ BT2,
                                              u16* __restrict__ Wot){
  const int bid = blockIdx.x, tid = threadIdx.x;
  if (bid < 12288){
    int i = bid*256 + tid;                       // < 3145728
    const float4 v = ((const float4*)x)[i];
    ushort4 h, l;
    split2(v.x, h.x, l.x);
    split2(v.y, h.y, l.y);
    split2(v.z, h.z, l.z);
    split2(v.w, h.w, l.w);
    ((ushort4*)Xh)[i] = h;
    ((ushort4*)Xl)[i] = l;
  } else if (bid < 21504){
    // BT1[1536][1536]: row c -> h=c>>7, g=(c>>6)&1 (0=Q,1=K), d=c&63; col k<768 hi / >=768 lo.
    int i = (bid - 12288)*256 + tid;             // < 2359296
    int c = i / 1536, k = i - c*1536;
    int seg = (k >= 768);
    int e = k - seg*768;
    int h = c >> 7, g = (c >> 6) & 1, d = c & 63;
    const float* W = g ? Wk : Wq;
    float v = W[((size_t)h*EE + e)*DD + d] * (g ? 1.0f : 0.125f*1.4426950408889634f);
    u16 hi, lo; split2(v, hi, lo);
    BT1[i] = seg ? lo : hi;
  } else if (bid < 23808){
    int i = (bid - 21504)*256 + tid;             // < 589824
    int c = i / 768, e = i - c*768;
    int h = c >> 6, d = c & 63;
    BT2[i] = f2bf(Wv[((size_t)h*EE + e)*DD + d]);
  } else {
    int i = (bid - 23808)*256 + tid;             // < 49152
    int j = i & 63, k = i >> 6;
    Wot[(size_t)j*EE + k] = f2bf(Wo[i]);
  }
}

// ---------------- Q/K projection (A-reuse, BK=32, 24 iters) — device body ----------------
// LDS rows are 64B (4x16B slots): both-sides XOR swizzle slot' = slot ^ ((row>>1)&3)
// -> quarter-wave ds_read_b128 spreads over all 8 bank-quads (was 8-way conflict).
DEV void do_qk(int flat, int tid, u16* lds,
               const u16* __restrict__ Xh, const u16* __restrict__ Xl,
               const u16* __restrict__ BT1,
               u16* __restrict__ Qh, u16* __restrict__ Ql,
               u16* __restrict__ Kh, u16* __restrict__ Kl){
  // lds layout: [buf][Xh,Xl,Wh,Wl][128*32]  (8 panels of 4096 u16 = 64 KB)
  const int swz = (flat & 7)*192 + (flat >> 3);  // XCD-chunked, bc fastest
  const int rt = swz / 12, bc = swz - rt*12;
  const int row0 = rt*128, col0 = bc*128;
  const int w = tid >> 6, l = tid & 63, lr = l & 15, lg = l >> 4;
  const int wr = w >> 1, wc = w & 1;
  const int sr = l >> 2;
  const int sce = ((l & 3) ^ ((l >> 3) & 3))*8;  // pre-swizzled source slot
  const int rcol = (lg ^ ((lr >> 1) & 3))*8;     // matching read slot

  f32x4 acc[4][4];
  #pragma unroll
  for (int m=0;m<4;++m)
    #pragma unroll
    for (int n=0;n<4;++n) acc[m][n] = f32x4{0.f,0.f,0.f,0.f};

  auto stage = [&](int buf, int kt){
    const int e0 = kt*32;
    #pragma unroll
    for (int j=0;j<2;++j){
      const int r = w*32 + j*16;
      const int gr = r + sr;
      u16* base = lds + buf*16384 + r*32;
      stage16(Xh  + (size_t)(row0 + gr)*EE   + e0 + sce,        base);
      stage16(Xl  + (size_t)(row0 + gr)*EE   + e0 + sce,        base + 4096);
      stage16(BT1 + (size_t)(col0 + gr)*1536 + e0 + sce,        base + 8192);
      stage16(BT1 + (size_t)(col0 + gr)*1536 + 768 + e0 + sce,  base + 12288);
    }
  };

  stage(0, 0);
  __syncthreads();

  for (int kt=0; kt<24; ++kt){
    const int buf = kt & 1;
    if (kt + 1 < 24) stage(buf ^ 1, kt + 1);

    bf16x8 ah[4], al[4], bh[4], bl[4];
    #pragma unroll
    for (int m=0;m<4;++m){
      const int off = buf*16384 + (wr*64 + m*16 + lr)*32 + rcol;
      ah[m] = ld8(lds + off);
      al[m] = ld8(lds + off + 4096);
    }
    #pragma unroll
    for (int n=0;n<4;++n){
      const int off = buf*16384 + (wc*64 + n*16 + lr)*32 + rcol;
      bh[n] = ld8(lds + off + 8192);
      bl[n] = ld8(lds + off + 12288);
    }

    __builtin_amdgcn_s_setprio(1);
    #pragma unroll
    for (int m=0;m<4;++m)
      #pragma unroll
      for (int n=0;n<4;++n){
        acc[m][n] = mfma16(ah[m], bh[n], acc[m][n]);
        acc[m][n] = mfma16(ah[m], bl[n], acc[m][n]);
        acc[m][n] = mfma16(al[m], bh[n], acc[m][n]);
      }
    __builtin_amdgcn_s_setprio(0);

    __syncthreads();
  }

  u16* Dh = wc ? Kh : Qh;
  u16* Dl = wc ? Kl : Ql;
  const size_t base = (size_t)bc*BN*DD;          // head = bc
  #pragma unroll
  for (int m=0;m<4;++m)
    #pragma unroll
    for (int n=0;n<4;++n)
      #pragma unroll
      for (int j=0;j<4;++j){
        int r = row0 + wr*64 + m*16 + lg*4 + j;
        int d = n*16 + lr;
        size_t o = base + (size_t)r*DD + d;
        u16 hi, lo; split2(acc[m][n][j], hi, lo);
        Dh[o] = hi; Dl[o] = lo;
      }
}

// ---------------- V projection (staged, 128x128, BK=64) — device body ----------------
// 128B rows (8x16B slots): swizzle slot' = slot ^ (row&7) (flash's K pattern).
DEV void do_v(int flat, int tid, u16* lds,
              const u16* __restrict__ Xh, const u16* __restrict__ BT,
              u16* __restrict__ Vt){
  // lds layout: [buf][A/B][128*64]  (4 panels of 8192 u16 = 64 KB)
  const int swz = (flat & 7)*96 + (flat >> 3);
  const int rt = swz / 6, bc = swz - rt*6;
  const int row0 = rt*128, col0 = bc*128;
  const int w = tid >> 6, l = tid & 63, lr = l & 15, lg = l >> 4;
  const int wr = w >> 1, wc = w & 1;
  const int sr = l >> 3;
  const int sce = ((l & 7) ^ sr)*8;              // pre-swizzled source slot

  f32x4 acc[4][4];
  #pragma unroll
  for (int m=0;m<4;++m)
    #pragma unroll
    for (int n=0;n<4;++n) acc[m][n] = f32x4{0.f,0.f,0.f,0.f};

  auto stage = [&](int buf, int kt){
    const int e0 = kt*64;
    const u16* ab = Xh + (size_t)row0*EE + e0 + sce;
    const u16* bb = BT + (size_t)col0*EE + e0 + sce;
    u16* la = lds + buf*16384;
    u16* lb = la + 8192;
    #pragma unroll
    for (int j=0;j<4;++j){
      const int it = j*4 + w;
      stage16(ab + (size_t)(it*8 + sr)*EE, la + it*512);
      stage16(bb + (size_t)(it*8 + sr)*EE, lb + it*512);
    }
  };

  stage(0, 0);
  __syncthreads();

  for (int kt=0; kt<12; ++kt){
    const int buf = kt & 1;
    if (kt + 1 < 12) stage(buf ^ 1, kt + 1);

    const u16* la = lds + buf*16384;
    const u16* lb = la + 8192;
    bf16x8 af[4][2], bfr[4][2];
    #pragma unroll
    for (int m=0;m<4;++m)
      #pragma unroll
      for (int ks=0;ks<2;++ks)
        af[m][ks] = ld8(la + (wr*64 + m*16 + lr)*64 + (((ks*4 + lg) ^ (lr & 7))*8));
    #pragma unroll
    for (int n=0;n<4;++n)
      #pragma unroll
      for (int ks=0;ks<2;++ks)
        bfr[n][ks] = ld8(lb + (wc*64 + n*16 + lr)*64 + (((ks*4 + lg) ^ (lr & 7))*8));

    #pragma unroll
    for (int ks=0;ks<2;++ks)
      #pragma unroll
      for (int m=0;m<4;++m)
        #pragma unroll
        for (int n=0;n<4;++n)
          acc[m][n] = mfma16(af[m][ks], bfr[n][ks], acc[m][n]);

    __syncthreads();
  }

  #pragma unroll
  for (int m=0;m<4;++m)
    #pragma unroll
    for (int n=0;n<4;++n){
      int c = col0 + wc*64 + n*16 + lr;
      int hh = c >> 6, d = c & 63;
      int r = row0 + wr*64 + m*16 + lg*4;
      int b = r >> 10, nn = r & 1023;
      // pre-permuted kv offset for flash PV frags
      int kvb = nn & ~63, kvL = nn & 63;
      int ks = kvL >> 5, rem = kvL & 31;
      int lgp = (rem >> 2) & 3, jh = rem >> 4;
      int off = kvb + ks*32 + lgp*8 + jh*4;
      ushort4 pk;
      pk.x = f2bf(acc[m][n][0]); pk.y = f2bf(acc[m][n][1]);
      pk.z = f2bf(acc[m][n][2]); pk.w = f2bf(acc[m][n][3]);
      *(ushort4*)(Vt + ((size_t)((hh*16 + b)*DD + d))*NN + off) = pk;
    }
}

// ---------------- uber projection kernel (QK blocks 0..1535, V blocks 1536..2303) ----------------
__global__ __launch_bounds__(256) void proj_k(const u16* __restrict__ Xh, const u16* __restrict__ Xl,
                                              const u16* __restrict__ BT1, const u16* __restrict__ BT2,
                                              u16* __restrict__ Qh, u16* __restrict__ Ql,
                                              u16* __restrict__ Kh, u16* __restrict__ Kl,
                                              u16* __restrict__ Vt){
  __shared__ u16 lds[32768];                     // 64 KB, shared by both bodies
  if (blockIdx.x < 1536)
    do_qk(blockIdx.x, threadIdx.x, lds, Xh, Xl, BT1, Qh, Ql, Kh, Kl);
  else
    do_v(blockIdx.x - 1536, threadIdx.x, lds, Xh, BT2, Vt);
}

// ---------------- flash attention: 8-wave blocks, quad-buffered K, barrier per 2 KV tiles ----------------
__global__ __launch_bounds__(512) void flash_k(const u16* __restrict__ Qh, const u16* __restrict__ Ql,
                                               const u16* __restrict__ Kh, const u16* __restrict__ Kl,
                                               const u16* __restrict__ Vt, u16* __restrict__ Cc){
  __shared__ u16 kbuf[4][2][4096];                 // [tilebuf][hi/lo][64*64] = 64 KB
  const int flat = blockIdx.x;                     // 768 = 8 XCD * 96
  const int swz = (flat & 7)*96 + (flat >> 3);     // XCD chunking: all blocks of a (b,h) share L2
  const int qb = swz & 3, bh = swz >> 2;
  const int h = bh % 12, b = bh / 12;
  const int l = threadIdx.x & 63, w = threadIdx.x >> 6, lr = l & 15, lg = l >> 4;
  const size_t hb = (size_t)h*BN*DD + (size_t)b*NN*DD;
  const int q0 = qb*256 + w*32;

  const int srow = l >> 3;
  const int scol = 8*((l & 7) ^ srow);

  auto stage = [&](int buf, int t){
    const int kv0 = t*64;
    #pragma unroll
    for (int j=0;j<2;++j){
      const int c = w*2 + j;                       // 16 chunks over 8 waves: 0-7 Kh, 8-15 Kl
      const u16* src = (c < 8) ? Kh : Kl;
      const int cr = (c & 7)*8;
      stage16(src + hb + (size_t)(kv0 + cr + srow)*DD + scol,
              &kbuf[buf][c >> 3][(c & 7)*512]);
    }
  };

  bf16x8 qfh[2][2], qfl[2][2];
  #pragma unroll
  for (int qf=0;qf<2;++qf)
    #pragma unroll
    for (int ks=0;ks<2;++ks){
      size_t o = hb + (size_t)(q0 + qf*16 + lr)*DD + ks*32 + lg*8;
      qfh[qf][ks] = ld8(Qh + o);
      qfl[qf][ks] = ld8(Ql + o);
    }

  // hoisted V pointers (pre-permuted Vt): advance +64 elems per KV tile
  const u16* vp[4];
  #pragma unroll
  for (int df=0;df<4;++df)
    vp[df] = Vt + ((size_t)((h*16 + b)*DD + df*16 + lr))*NN + lg*8;

  f32x4 acc[2][4];                 // [qf][df] : O^T frags (row=d, col=q)
  float mr[2] = {-1e30f,-1e30f}, ls[2] = {0.f,0.f};   // ls = per-lane partial
  #pragma unroll
  for (int qf=0;qf<2;++qf)
    #pragma unroll
    for (int df=0;df<4;++df) acc[qf][df] = f32x4{0.f,0.f,0.f,0.f};

  auto tb = [&](int buf){
    // V^T A-frags first (oldest vmem ops)
    bf16x8 va[4][2];
    #pragma unroll
    for (int df=0;df<4;++df){
      va[df][0] = ld8(vp[df]);
      va[df][1] = ld8(vp[df] + 32);
      vp[df] += 64;
    }

    f32x4 s[2][4];                 // [qf][kf]
    #pragma unroll
    for (int qf=0;qf<2;++qf)
      #pragma unroll
      for (int kf=0;kf<4;++kf) s[qf][kf] = f32x4{0.f,0.f,0.f,0.f};

    const char* kb = (const char*)&kbuf[buf][0][0];
    #pragma unroll
    for (int ks=0;ks<2;++ks){
      bf16x8 kh[4], kl2[4];
      #pragma unroll
      for (int kf=0;kf<4;++kf){
        const int r = kf*16 + lr;
        const int sw = (ks*64 + lg*16) ^ ((lr & 7) << 4);
        kh[kf]  = *(const bf16x8*)(kb + r*128 + sw);
        kl2[kf] = *(const bf16x8*)(kb + 8192 + r*128 + sw);
      }
      __builtin_amdgcn_s_setprio(1);
      #pragma unroll
      for (int qf=0;qf<2;++qf)
        #pragma unroll
        for (int kf=0;kf<4;++kf){
          s[qf][kf] = mfma16(kh[kf],  qfh[qf][ks], s[qf][kf]);
          s[qf][kf] = mfma16(kl2[kf], qfh[qf][ks], s[qf][kf]);
          s[qf][kf] = mfma16(kh[kf],  qfl[qf][ks], s[qf][kf]);
        }
      __builtin_amdgcn_s_setprio(0);
    }

    // softmax (exp2 domain; lazy group rescale; per lane: 2 q-rows)
    bf16x8 pb[2][2];
    #pragma unroll
    for (int qf=0;qf<2;++qf){
      float a0 = fmaxf(fmaxf(s[qf][0][0], s[qf][0][1]), fmaxf(s[qf][0][2], s[qf][0][3]));
      float a1 = fmaxf(fmaxf(s[qf][1][0], s[qf][1][1]), fmaxf(s[qf][1][2], s[qf][1][3]));
      float a2 = fmaxf(fmaxf(s[qf][2][0], s[qf][2][1]), fmaxf(s[qf][2][2], s[qf][2][3]));
      float a3 = fmaxf(fmaxf(s[qf][3][0], s[qf][3][1]), fmaxf(s[qf][3][2], s[qf][3][3]));
      float pm = fmaxf(fmaxf(a0, a1), fmaxf(a2, a3));
      if (__any(pm > mr[qf] + 8.f)){               // max growth -> rescale
        pm = fmaxf(pm, __shfl_xor(pm, 16, 64));
        pm = fmaxf(pm, __shfl_xor(pm, 32, 64));
        const float mn = fmaxf(mr[qf], pm);
        const float fs = fexp2(mr[qf] - mn);
        mr[qf] = mn;
        ls[qf] *= fs;
        #pragma unroll
        for (int df=0;df<4;++df)
          #pragma unroll
          for (int r=0;r<4;++r) acc[qf][df][r] *= fs;
      }
      float rs = 0.f;
      #pragma unroll
      for (int kf=0;kf<4;++kf)
        #pragma unroll
        for (int r=0;r<4;++r){
          float e = fexp2(s[qf][kf][r] - mr[qf]);  // bounded by 2^8; underflow->0 fine
          s[qf][kf][r] = e;
          rs += e;
        }
      ls[qf] += rs;
      #pragma unroll
      for (int ks=0;ks<2;++ks){
        U8 pu;
        pu.w[0] = pk2(s[qf][2*ks][0],   s[qf][2*ks][1]);
        pu.w[1] = pk2(s[qf][2*ks][2],   s[qf][2*ks][3]);
        pu.w[2] = pk2(s[qf][2*ks+1][0], s[qf][2*ks+1][1]);
        pu.w[3] = pk2(s[qf][2*ks+1][2], s[qf][2*ks+1][3]);
        pb[qf][ks] = pu.v;
      }
    }

    // PV: O^T += V^T * P  (bf16)
    __builtin_amdgcn_s_setprio(1);
    #pragma unroll
    for (int ks=0;ks<2;++ks)
      #pragma unroll
      for (int qf=0;qf<2;++qf)
        #pragma unroll
        for (int df=0;df<4;++df)
          acc[qf][df] = mfma16(va[df][ks], pb[qf][ks], acc[qf][df]);
    __builtin_amdgcn_s_setprio(0);
  };

  stage(0, 0);
  stage(1, 1);
  __syncthreads();

  for (int ss=0; ss<8; ++ss){
    const int cur = (ss & 1) << 1;                 // 0 or 2
    if (ss < 7){
      stage(cur ^ 2,       2*ss + 2);              // prefetch next tile pair
      stage((cur ^ 2) + 1, 2*ss + 3);
    }
    tb(cur);                                       // tile 2ss
    tb(cur + 1);                                   // tile 2ss+1
    __syncthreads();                               // one barrier per 2 tiles
  }

  #pragma unroll
  for (int qf=0;qf<2;++qf){
    float t1 = ls[qf] + __shfl_xor(ls[qf], 16, 64);
    t1 += __shfl_xor(t1, 32, 64);
    const float inv = 1.0f / t1;
    #pragma unroll
    for (int df=0;df<4;++df){
      ushort4 o4;
      o4.x = f2bf(acc[qf][df][0]*inv);
      o4.y = f2bf(acc[qf][df][1]*inv);
      o4.z = f2bf(acc[qf][df][2]*inv);
      o4.w = f2bf(acc[qf][df][3]*inv);
      *(ushort4*)(Cc + (size_t)(b*NN + q0 + qf*16 + lr)*EE + h*DD + df*16 + lg*4) = o4;
    }
  }
}

// ---------------- output projection (staged, 64-row tiles, BK=64, swizzled) ----------------
__global__ __launch_bounds__(256) void gemm_o_k(const u16* __restrict__ Cc, const u16* __restrict__ Wot,
                                                float* __restrict__ out){
  __shared__ u16 lds[2][2][4096];                // [buf][A/B][64*64] = 32 KB
  const int rt = blockIdx.x;                     // 256 blocks x 64 rows
  const int tid = threadIdx.x;
  const int w = tid >> 6, l = tid & 63, lr = l & 15, lg = l >> 4;
  const int row0 = rt*64;
  const int sr = l >> 3;
  const int sce = ((l & 7) ^ sr)*8;              // pre-swizzled source slot

  f32x4 acc[4];
  #pragma unroll
  for (int n=0;n<4;++n) acc[n] = f32x4{0.f,0.f,0.f,0.f};

  auto stage = [&](int buf, int kt){
    const int e0 = kt*64;
    #pragma unroll
    for (int j=0;j<2;++j){
      const int r = w*16 + j*8;
      stage16(Cc  + (size_t)(row0 + r + sr)*EE + e0 + sce, &lds[buf][0][r*64]);
      stage16(Wot + (size_t)(r + sr)*EE        + e0 + sce, &lds[buf][1][r*64]);
    }
  };

  stage(0, 0);
  __syncthreads();

  for (int kt=0; kt<12; ++kt){
    const int buf = kt & 1;
    if (kt + 1 < 12) stage(buf ^ 1, kt + 1);

    bf16x8 a[2], bb[4][2];
    #pragma unroll
    for (int ks=0;ks<2;++ks)
      a[ks] = ld8(&lds[buf][0][(w*16 + lr)*64 + (((ks*4 + lg) ^ (lr & 7))*8)]);
    #pragma unroll
    for (int nf=0;nf<4;++nf)
      #pragma unroll
      for (int ks=0;ks<2;++ks)
        bb[nf][ks] = ld8(&lds[buf][1][(nf*16 + lr)*64 + (((ks*4 + lg) ^ (lr & 7))*8)]);

    #pragma unroll
    for (int ks=0;ks<2;++ks)
      #pragma unroll
      for (int nf=0;nf<4;++nf)
        acc[nf] = mfma16(a[ks], bb[nf][ks], acc[nf]);

    __syncthreads();
  }

  #pragma unroll
  for (int nf=0;nf<4;++nf)
    #pragma unroll
    for (int j=0;j<4;++j)
      out[(size_t)(row0 + w*16 + lg*4 + j)*DD + nf*16 + lr] = acc[nf][j];
}

// ---------------- launch ----------------
extern "C" void kernel_launch(void* const* d_in, const int* in_sizes, int n_in,
                              void* d_out, int out_size, void* d_ws, size_t ws_size,
                              hipStream_t stream) {
  const float* x  = (const float*)d_in[0];
  const float* Wq = (const float*)d_in[1];
  const float* Wk = (const float*)d_in[2];
  const float* Wv = (const float*)d_in[3];
  const float* Wo = (const float*)d_in[4];
  float* out = (float*)d_out;

  u16* ws = (u16*)d_ws;
  const size_t SB = (size_t)12582912;   // 16384*768
  u16* Xh  = ws;
  u16* Xl  = Xh + SB;
  u16* Qh  = Xl + SB;
  u16* Ql  = Qh + SB;
  u16* Kh  = Ql + SB;
  u16* Kl  = Kh + SB;
  u16* Vt  = Kl + SB;
  u16* Cc  = Vt + SB;
  u16* Wot = Cc + SB;
  // BT1/BT2 alias into Cc: written by prep, read by proj, then Cc is fully
  // overwritten by flash_k before gemm_o_k reads it (in-stream ordering).
  u16* BT1 = Cc;                        // 1536*1536 = 2359296 elems
  u16* BT2 = Cc + 2359296;              // 768*768   =  589824 elems

  prep_k<<<24000, 256, 0, stream>>>(x, Wq, Wk, Wv, Wo, Xh, Xl, BT1, BT2, Wot);
  proj_k<<<2304,  256, 0, stream>>>(Xh, Xl, BT1, BT2, Qh, Ql, Kh, Kl, Vt);
  flash_k<<<768,  512, 0, stream>>>(Qh, Ql, Kh, Kl, Vt, Cc);
  gemm_o_k<<<256, 256, 0, stream>>>(Cc, Wot, out);
}

// Round 13
// 292.403 us; speedup vs baseline: 1.7244x; 1.0064x over previous
//
#include <hip/hip_runtime.h>
#include <hip/hip_bf16.h>

typedef unsigned short u16;
typedef unsigned int u32;
typedef __attribute__((ext_vector_type(8))) short bf16x8;   // 8x16-bit in 4 VGPRs
typedef __attribute__((ext_vector_type(4))) float f32x4;

#define DEV static __device__ __forceinline__

#define BB 16
#define NN 1024
#define EE 768
#define HH 12
#define DD 64
#define BN (BB*NN)   // 16384

DEV u16 f2bf(float f){ __hip_bfloat16 h = __float2bfloat16(f); u16 u; __builtin_memcpy(&u, &h, 2); return u; }
DEV float bf2f(u16 u){ __hip_bfloat16 h; __builtin_memcpy(&h, &u, 2); return __bfloat162float(h); }
DEV void split2(float v, u16& hi, u16& lo){ hi = f2bf(v); lo = f2bf(v - bf2f(hi)); }
DEV bf16x8 ld8(const u16* p){ return *(const bf16x8*)p; }
DEV f32x4 mfma16(bf16x8 a, bf16x8 b, f32x4 c){ return __builtin_amdgcn_mfma_f32_16x16x32_bf16(a, b, c, 0, 0, 0); }
DEV float fexp2(float x){ return __builtin_amdgcn_exp2f(x); }   // raw v_exp_f32; underflow->0 is wanted
DEV float max3f(float a, float b, float c){ return fmaxf(fmaxf(a, b), c); }  // fuses to v_max3_f32
DEV u32 pk2(float a, float b){                       // 2xf32 -> packed 2xbf16 (v_cvt_pk_bf16_f32)
  float2 f{a, b};
  __hip_bfloat162 t = __float22bfloat162_rn(f);
  u32 r; __builtin_memcpy(&r, &t, 4); return r;
}

union U8 { bf16x8 v; u16 e[8]; ushort4 q[2]; u32 w[4]; };

// async global->LDS, 16B per lane. LDS dst must be wave-uniform; HW adds lane*16.
DEV void stage16(const u16* g, u16* l){
  __builtin_amdgcn_global_load_lds((const __attribute__((address_space(1))) void*)g,
                                   (__attribute__((address_space(3))) void*)l,
                                   16, 0, 0);
}

// ---------------- uber prep kernel (split_x + pack_bt1 + pack_bt2 + pack_wo) ----------------
__global__ __launch_bounds__(256) void prep_k(const float* __restrict__ x,
                                              const float* __restrict__ Wq,
                                              const float* __restrict__ Wk,
                                              const float* __restrict__ Wv,
                                              const float* __restrict__ Wo,
                                              u16* __restrict__ Xh, u16* __restrict__ Xl,
                                              u16* __restrict__ BT1, u16* __restrict__ BT2,
                                              u16* __restrict__ Wot){
  const int bid = blockIdx.x, tid = threadIdx.x;
  if (bid < 12288){
    int i = bid*256 + tid;                       // < 3145728
    const float4 v = ((const float4*)x)[i];
    ushort4 h, l;
    split2(v.x, h.x, l.x);
    split2(v.y, h.y, l.y);
    split2(v.z, h.z, l.z);
    split2(v.w, h.w, l.w);
    ((ushort4*)Xh)[i] = h;
    ((ushort4*)Xl)[i] = l;
  } else if (bid < 21504){
    // BT1[1536][1536]: row c -> h=c>>7, g=(c>>6)&1 (0=Q,1=K), d=c&63; col k<768 hi / >=768 lo.
    int i = (bid - 12288)*256 + tid;             // < 2359296
    int c = i / 1536, k = i - c*1536;
    int seg = (k >= 768);
    int e = k - seg*768;
    int h = c >> 7, g = (c >> 6) & 1, d = c & 63;
    const float* W = g ? Wk : Wq;
    float v = W[((size_t)h*EE + e)*DD + d] * (g ? 1.0f : 0.125f*1.4426950408889634f);
    u16 hi, lo; split2(v, hi, lo);
    BT1[i] = seg ? lo : hi;
  } else if (bid < 23808){
    int i = (bid - 21504)*256 + tid;             // < 589824
    int c = i / 768, e = i - c*768;
    int h = c >> 6, d = c & 63;
    BT2[i] = f2bf(Wv[((size_t)h*EE + e)*DD + d]);
  } else {
    int i = (bid - 23808)*256 + tid;             // < 49152
    int j = i & 63, k = i >> 6;
    Wot[(size_t)j*EE + k] = f2bf(Wo[i]);
  }
}

// ---------------- Q/K projection (A-reuse, BK=32, 24 iters) — device body ----------------
// 64B rows (4x16B slots): both-sides XOR swizzle slot' = slot ^ ((row>>1)&3).
DEV void do_qk(int flat, int tid, u16* lds,
               const u16* __restrict__ Xh, const u16* __restrict__ Xl,
               const u16* __restrict__ BT1,
               u16* __restrict__ Qh, u16* __restrict__ Ql,
               u16* __restrict__ Kh, u16* __restrict__ Kl){
  // lds layout: [buf][Xh,Xl,Wh,Wl][128*32]  (8 panels of 4096 u16 = 64 KB)
  const int swz = (flat & 7)*192 + (flat >> 3);  // XCD-chunked, bc fastest
  const int rt = swz / 12, bc = swz - rt*12;
  const int row0 = rt*128, col0 = bc*128;
  const int w = tid >> 6, l = tid & 63, lr = l & 15, lg = l >> 4;
  const int wr = w >> 1, wc = w & 1;
  const int sr = l >> 2;
  const int sce = ((l & 3) ^ ((l >> 3) & 3))*8;  // pre-swizzled source slot
  const int rcol = (lg ^ ((lr >> 1) & 3))*8;     // matching read slot

  f32x4 acc[4][4];
  #pragma unroll
  for (int m=0;m<4;++m)
    #pragma unroll
    for (int n=0;n<4;++n) acc[m][n] = f32x4{0.f,0.f,0.f,0.f};

  auto stage = [&](int buf, int kt){
    const int e0 = kt*32;
    #pragma unroll
    for (int j=0;j<2;++j){
      const int r = w*32 + j*16;
      const int gr = r + sr;
      u16* base = lds + buf*16384 + r*32;
      stage16(Xh  + (size_t)(row0 + gr)*EE   + e0 + sce,        base);
      stage16(Xl  + (size_t)(row0 + gr)*EE   + e0 + sce,        base + 4096);
      stage16(BT1 + (size_t)(col0 + gr)*1536 + e0 + sce,        base + 8192);
      stage16(BT1 + (size_t)(col0 + gr)*1536 + 768 + e0 + sce,  base + 12288);
    }
  };

  stage(0, 0);
  __syncthreads();

  for (int kt=0; kt<24; ++kt){
    const int buf = kt & 1;
    if (kt + 1 < 24) stage(buf ^ 1, kt + 1);

    bf16x8 ah[4], al[4], bh[4], bl[4];
    #pragma unroll
    for (int m=0;m<4;++m){
      const int off = buf*16384 + (wr*64 + m*16 + lr)*32 + rcol;
      ah[m] = ld8(lds + off);
      al[m] = ld8(lds + off + 4096);
    }
    #pragma unroll
    for (int n=0;n<4;++n){
      const int off = buf*16384 + (wc*64 + n*16 + lr)*32 + rcol;
      bh[n] = ld8(lds + off + 8192);
      bl[n] = ld8(lds + off + 12288);
    }

    __builtin_amdgcn_s_setprio(1);
    #pragma unroll
    for (int m=0;m<4;++m)
      #pragma unroll
      for (int n=0;n<4;++n){
        acc[m][n] = mfma16(ah[m], bh[n], acc[m][n]);
        acc[m][n] = mfma16(ah[m], bl[n], acc[m][n]);
        acc[m][n] = mfma16(al[m], bh[n], acc[m][n]);
      }
    __builtin_amdgcn_s_setprio(0);

    __syncthreads();
  }

  u16* Dh = wc ? Kh : Qh;
  u16* Dl = wc ? Kl : Ql;
  const size_t base = (size_t)bc*BN*DD;          // head = bc
  #pragma unroll
  for (int m=0;m<4;++m)
    #pragma unroll
    for (int n=0;n<4;++n)
      #pragma unroll
      for (int j=0;j<4;++j){
        int r = row0 + wr*64 + m*16 + lg*4 + j;
        int d = n*16 + lr;
        size_t o = base + (size_t)r*DD + d;
        u16 hi, lo; split2(acc[m][n][j], hi, lo);
        Dh[o] = hi; Dl[o] = lo;
      }
}

// ---------------- V projection (staged, 128x128, BK=64) — device body ----------------
// 128B rows (8x16B slots): swizzle slot' = slot ^ (row&7).
DEV void do_v(int flat, int tid, u16* lds,
              const u16* __restrict__ Xh, const u16* __restrict__ BT,
              u16* __restrict__ Vt){
  // lds layout: [buf][A/B][128*64]  (4 panels of 8192 u16 = 64 KB)
  const int swz = (flat & 7)*96 + (flat >> 3);
  const int rt = swz / 6, bc = swz - rt*6;
  const int row0 = rt*128, col0 = bc*128;
  const int w = tid >> 6, l = tid & 63, lr = l & 15, lg = l >> 4;
  const int wr = w >> 1, wc = w & 1;
  const int sr = l >> 3;
  const int sce = ((l & 7) ^ sr)*8;              // pre-swizzled source slot

  f32x4 acc[4][4];
  #pragma unroll
  for (int m=0;m<4;++m)
    #pragma unroll
    for (int n=0;n<4;++n) acc[m][n] = f32x4{0.f,0.f,0.f,0.f};

  auto stage = [&](int buf, int kt){
    const int e0 = kt*64;
    const u16* ab = Xh + (size_t)row0*EE + e0 + sce;
    const u16* bb = BT + (size_t)col0*EE + e0 + sce;
    u16* la = lds + buf*16384;
    u16* lb = la + 8192;
    #pragma unroll
    for (int j=0;j<4;++j){
      const int it = j*4 + w;
      stage16(ab + (size_t)(it*8 + sr)*EE, la + it*512);
      stage16(bb + (size_t)(it*8 + sr)*EE, lb + it*512);
    }
  };

  stage(0, 0);
  __syncthreads();

  for (int kt=0; kt<12; ++kt){
    const int buf = kt & 1;
    if (kt + 1 < 12) stage(buf ^ 1, kt + 1);

    const u16* la = lds + buf*16384;
    const u16* lb = la + 8192;
    bf16x8 af[4][2], bfr[4][2];
    #pragma unroll
    for (int m=0;m<4;++m)
      #pragma unroll
      for (int ks=0;ks<2;++ks)
        af[m][ks] = ld8(la + (wr*64 + m*16 + lr)*64 + (((ks*4 + lg) ^ (lr & 7))*8));
    #pragma unroll
    for (int n=0;n<4;++n)
      #pragma unroll
      for (int ks=0;ks<2;++ks)
        bfr[n][ks] = ld8(lb + (wc*64 + n*16 + lr)*64 + (((ks*4 + lg) ^ (lr & 7))*8));

    #pragma unroll
    for (int ks=0;ks<2;++ks)
      #pragma unroll
      for (int m=0;m<4;++m)
        #pragma unroll
        for (int n=0;n<4;++n)
          acc[m][n] = mfma16(af[m][ks], bfr[n][ks], acc[m][n]);

    __syncthreads();
  }

  #pragma unroll
  for (int m=0;m<4;++m)
    #pragma unroll
    for (int n=0;n<4;++n){
      int c = col0 + wc*64 + n*16 + lr;
      int hh = c >> 6, d = c & 63;
      int r = row0 + wr*64 + m*16 + lg*4;
      int b = r >> 10, nn = r & 1023;
      // pre-permuted kv offset for flash PV frags
      int kvb = nn & ~63, kvL = nn & 63;
      int ks = kvL >> 5, rem = kvL & 31;
      int lgp = (rem >> 2) & 3, jh = rem >> 4;
      int off = kvb + ks*32 + lgp*8 + jh*4;
      ushort4 pk;
      pk.x = f2bf(acc[m][n][0]); pk.y = f2bf(acc[m][n][1]);
      pk.z = f2bf(acc[m][n][2]); pk.w = f2bf(acc[m][n][3]);
      *(ushort4*)(Vt + ((size_t)((hh*16 + b)*DD + d))*NN + off) = pk;
    }
}

// ---------------- uber projection kernel (QK blocks 0..1535, V blocks 1536..2303) ----------------
__global__ __launch_bounds__(256) void proj_k(const u16* __restrict__ Xh, const u16* __restrict__ Xl,
                                              const u16* __restrict__ BT1, const u16* __restrict__ BT2,
                                              u16* __restrict__ Qh, u16* __restrict__ Ql,
                                              u16* __restrict__ Kh, u16* __restrict__ Kl,
                                              u16* __restrict__ Vt){
  __shared__ u16 lds[32768];                     // 64 KB, shared by both bodies
  if (blockIdx.x < 1536)
    do_qk(blockIdx.x, threadIdx.x, lds, Xh, Xl, BT1, Qh, Ql, Kh, Kl);
  else
    do_v(blockIdx.x - 1536, threadIdx.x, lds, Xh, BT2, Vt);
}

// ---------------- flash attention: 8-wave blocks, quad-buffered K, barrier per 2 KV tiles ----------------
// This round: packed-f32 softmax arithmetic, v_max3 lane-max tree, split va loads
// (va[0..1] at body start, va[2..3] after QK MFMAs) to halve the va live-range.
__global__ __launch_bounds__(512) void flash_k(const u16* __restrict__ Qh, const u16* __restrict__ Ql,
                                               const u16* __restrict__ Kh, const u16* __restrict__ Kl,
                                               const u16* __restrict__ Vt, u16* __restrict__ Cc){
  __shared__ u16 kbuf[4][2][4096];                 // [tilebuf][hi/lo][64*64] = 64 KB
  const int flat = blockIdx.x;                     // 768 = 8 XCD * 96
  const int swz = (flat & 7)*96 + (flat >> 3);     // XCD chunking: all blocks of a (b,h) share L2
  const int qb = swz & 3, bh = swz >> 2;
  const int h = bh % 12, b = bh / 12;
  const int l = threadIdx.x & 63, w = threadIdx.x >> 6, lr = l & 15, lg = l >> 4;
  const size_t hb = (size_t)h*BN*DD + (size_t)b*NN*DD;
  const int q0 = qb*256 + w*32;

  const int srow = l >> 3;
  const int scol = 8*((l & 7) ^ srow);

  auto stage = [&](int buf, int t){
    const int kv0 = t*64;
    #pragma unroll
    for (int j=0;j<2;++j){
      const int c = w*2 + j;                       // 16 chunks over 8 waves: 0-7 Kh, 8-15 Kl
      const u16* src = (c < 8) ? Kh : Kl;
      const int cr = (c & 7)*8;
      stage16(src + hb + (size_t)(kv0 + cr + srow)*DD + scol,
              &kbuf[buf][c >> 3][(c & 7)*512]);
    }
  };

  bf16x8 qfh[2][2], qfl[2][2];
  #pragma unroll
  for (int qf=0;qf<2;++qf)
    #pragma unroll
    for (int ks=0;ks<2;++ks){
      size_t o = hb + (size_t)(q0 + qf*16 + lr)*DD + ks*32 + lg*8;
      qfh[qf][ks] = ld8(Qh + o);
      qfl[qf][ks] = ld8(Ql + o);
    }

  // hoisted V pointers (pre-permuted Vt): advance +64 elems per KV tile
  const u16* vp[4];
  #pragma unroll
  for (int df=0;df<4;++df)
    vp[df] = Vt + ((size_t)((h*16 + b)*DD + df*16 + lr))*NN + lg*8;

  f32x4 acc[2][4];                 // [qf][df] : O^T frags (row=d, col=q)
  float mr[2] = {-1e30f,-1e30f}, ls[2] = {0.f,0.f};   // ls = per-lane partial
  #pragma unroll
  for (int qf=0;qf<2;++qf)
    #pragma unroll
    for (int df=0;df<4;++df) acc[qf][df] = f32x4{0.f,0.f,0.f,0.f};

  auto tb = [&](int buf){
    // V^T A-frags, first half (df 0..1) — issued earliest
    bf16x8 va01[2][2];
    #pragma unroll
    for (int df=0;df<2;++df){
      va01[df][0] = ld8(vp[df]);
      va01[df][1] = ld8(vp[df] + 32);
      vp[df] += 64;
    }

    f32x4 s[2][4];                 // [qf][kf]
    #pragma unroll
    for (int qf=0;qf<2;++qf)
      #pragma unroll
      for (int kf=0;kf<4;++kf) s[qf][kf] = f32x4{0.f,0.f,0.f,0.f};

    const char* kb = (const char*)&kbuf[buf][0][0];
    #pragma unroll
    for (int ks=0;ks<2;++ks){
      bf16x8 kh[4], kl2[4];
      #pragma unroll
      for (int kf=0;kf<4;++kf){
        const int r = kf*16 + lr;
        const int sw = (ks*64 + lg*16) ^ ((lr & 7) << 4);
        kh[kf]  = *(const bf16x8*)(kb + r*128 + sw);
        kl2[kf] = *(const bf16x8*)(kb + 8192 + r*128 + sw);
      }
      __builtin_amdgcn_s_setprio(1);
      #pragma unroll
      for (int qf=0;qf<2;++qf)
        #pragma unroll
        for (int kf=0;kf<4;++kf){
          s[qf][kf] = mfma16(kh[kf],  qfh[qf][ks], s[qf][kf]);
          s[qf][kf] = mfma16(kl2[kf], qfh[qf][ks], s[qf][kf]);
          s[qf][kf] = mfma16(kh[kf],  qfl[qf][ks], s[qf][kf]);
        }
      __builtin_amdgcn_s_setprio(0);
    }

    // V^T A-frags, second half (df 2..3) — latency hides under softmax below
    bf16x8 va23[2][2];
    #pragma unroll
    for (int df=0;df<2;++df){
      va23[df][0] = ld8(vp[df+2]);
      va23[df][1] = ld8(vp[df+2] + 32);
      vp[df+2] += 64;
    }

    // softmax (exp2 domain; lazy group rescale; packed-f32 arithmetic; per lane: 2 q-rows)
    bf16x8 pb[2][2];
    #pragma unroll
    for (int qf=0;qf<2;++qf){
      const f32x4 s0 = s[qf][0], s1 = s[qf][1], s2 = s[qf][2], s3 = s[qf][3];
      float m0 = max3f(s0[0], s0[1], s0[2]);
      float m1 = max3f(s0[3], s1[0], s1[1]);
      float m2 = max3f(s1[2], s1[3], s2[0]);
      float m3 = max3f(s2[1], s2[2], s2[3]);
      float m4 = max3f(s3[0], s3[1], s3[2]);
      float pm = fmaxf(max3f(m0, m1, m2), max3f(m3, m4, s3[3]));
      if (__any(pm > mr[qf] + 8.f)){               // max growth -> rescale
        pm = fmaxf(pm, __shfl_xor(pm, 16, 64));
        pm = fmaxf(pm, __shfl_xor(pm, 32, 64));
        const float mn = fmaxf(mr[qf], pm);
        const float fs = fexp2(mr[qf] - mn);
        mr[qf] = mn;
        ls[qf] *= fs;
        #pragma unroll
        for (int df=0;df<4;++df) acc[qf][df] *= fs;  // vector-scalar mul (v_pk)
      }
      f32x4 rsv = f32x4{0.f,0.f,0.f,0.f};
      const float mrq = mr[qf];
      #pragma unroll
      for (int kf=0;kf<4;++kf){
        f32x4 d = s[qf][kf] - mrq;                 // vector-scalar sub (v_pk)
        f32x4 e;
        e[0] = fexp2(d[0]); e[1] = fexp2(d[1]);
        e[2] = fexp2(d[2]); e[3] = fexp2(d[3]);
        s[qf][kf] = e;
        rsv += e;                                  // vector add (v_pk)
      }
      ls[qf] += (rsv[0] + rsv[1]) + (rsv[2] + rsv[3]);
      #pragma unroll
      for (int ks=0;ks<2;++ks){
        U8 pu;
        pu.w[0] = pk2(s[qf][2*ks][0],   s[qf][2*ks][1]);
        pu.w[1] = pk2(s[qf][2*ks][2],   s[qf][2*ks][3]);
        pu.w[2] = pk2(s[qf][2*ks+1][0], s[qf][2*ks+1][1]);
        pu.w[3] = pk2(s[qf][2*ks+1][2], s[qf][2*ks+1][3]);
        pb[qf][ks] = pu.v;
      }
    }

    // PV: O^T += V^T * P  (bf16); df 0..1 from va01, df 2..3 from va23
    __builtin_amdgcn_s_setprio(1);
    #pragma unroll
    for (int ks=0;ks<2;++ks)
      #pragma unroll
      for (int qf=0;qf<2;++qf){
        #pragma unroll
        for (int df=0;df<2;++df)
          acc[qf][df] = mfma16(va01[df][ks], pb[qf][ks], acc[qf][df]);
        #pragma unroll
        for (int df=0;df<2;++df)
          acc[qf][df+2] = mfma16(va23[df][ks], pb[qf][ks], acc[qf][df+2]);
      }
    __builtin_amdgcn_s_setprio(0);
  };

  stage(0, 0);
  stage(1, 1);
  __syncthreads();

  for (int ss=0; ss<8; ++ss){
    const int cur = (ss & 1) << 1;                 // 0 or 2
    if (ss < 7){
      stage(cur ^ 2,       2*ss + 2);              // prefetch next tile pair
      stage((cur ^ 2) + 1, 2*ss + 3);
    }
    tb(cur);                                       // tile 2ss
    tb(cur + 1);                                   // tile 2ss+1
    __syncthreads();                               // one barrier per 2 tiles
  }

  #pragma unroll
  for (int qf=0;qf<2;++qf){
    float t1 = ls[qf] + __shfl_xor(ls[qf], 16, 64);
    t1 += __shfl_xor(t1, 32, 64);
    const float inv = 1.0f / t1;
    #pragma unroll
    for (int df=0;df<4;++df){
      ushort4 o4;
      o4.x = f2bf(acc[qf][df][0]*inv);
      o4.y = f2bf(acc[qf][df][1]*inv);
      o4.z = f2bf(acc[qf][df][2]*inv);
      o4.w = f2bf(acc[qf][df][3]*inv);
      *(ushort4*)(Cc + (size_t)(b*NN + q0 + qf*16 + lr)*EE + h*DD + df*16 + lg*4) = o4;
    }
  }
}

// ---------------- output projection (staged, 64-row tiles, BK=64, swizzled) ----------------
__global__ __launch_bounds__(256) void gemm_o_k(const u16* __restrict__ Cc, const u16* __restrict__ Wot,
                                                float* __restrict__ out){
  __shared__ u16 lds[2][2][4096];                // [buf][A/B][64*64] = 32 KB
  const int rt = blockIdx.x;                     // 256 blocks x 64 rows
  const int tid = threadIdx.x;
  const int w = tid >> 6, l = tid & 63, lr = l & 15, lg = l >> 4;
  const int row0 = rt*64;
  const int sr = l >> 3;
  const int sce = ((l & 7) ^ sr)*8;              // pre-swizzled source slot

  f32x4 acc[4];
  #pragma unroll
  for (int n=0;n<4;++n) acc[n] = f32x4{0.f,0.f,0.f,0.f};

  auto stage = [&](int buf, int kt){
    const int e0 = kt*64;
    #pragma unroll
    for (int j=0;j<2;++j){
      const int r = w*16 + j*8;
      stage16(Cc  + (size_t)(row0 + r + sr)*EE + e0 + sce, &lds[buf][0][r*64]);
      stage16(Wot + (size_t)(r + sr)*EE        + e0 + sce, &lds[buf][1][r*64]);
    }
  };

  stage(0, 0);
  __syncthreads();

  for (int kt=0; kt<12; ++kt){
    const int buf = kt & 1;
    if (kt + 1 < 12) stage(buf ^ 1, kt + 1);

    bf16x8 a[2], bb[4][2];
    #pragma unroll
    for (int ks=0;ks<2;++ks)
      a[ks] = ld8(&lds[buf][0][(w*16 + lr)*64 + (((ks*4 + lg) ^ (lr & 7))*8)]);
    #pragma unroll
    for (int nf=0;nf<4;++nf)
      #pragma unroll
      for (int ks=0;ks<2;++ks)
        bb[nf][ks] = ld8(&lds[buf][1][(nf*16 + lr)*64 + (((ks*4 + lg) ^ (lr & 7))*8)]);

    #pragma unroll
    for (int ks=0;ks<2;++ks)
      #pragma unroll
      for (int nf=0;nf<4;++nf)
        acc[nf] = mfma16(a[ks], bb[nf][ks], acc[nf]);

    __syncthreads();
  }

  #pragma unroll
  for (int nf=0;nf<4;++nf)
    #pragma unroll
    for (int j=0;j<4;++j)
      out[(size_t)(row0 + w*16 + lg*4 + j)*DD + nf*16 + lr] = acc[nf][j];
}

// ---------------- launch ----------------
extern "C" void kernel_launch(void* const* d_in, const int* in_sizes, int n_in,
                              void* d_out, int out_size, void* d_ws, size_t ws_size,
                              hipStream_t stream) {
  const float* x  = (const float*)d_in[0];
  const float* Wq = (const float*)d_in[1];
  const float* Wk = (const float*)d_in[2];
  const float* Wv = (const float*)d_in[3];
  const float* Wo = (const float*)d_in[4];
  float* out = (float*)d_out;

  u16* ws = (u16*)d_ws;
  const size_t SB = (size_t)12582912;   // 16384*768
  u16* Xh  = ws;
  u16* Xl  = Xh + SB;
  u16* Qh  = Xl + SB;
  u16* Ql  = Qh + SB;
  u16* Kh  = Ql + SB;
  u16* Kl  = Kh + SB;
  u16* Vt  = Kl + SB;
  u16* Cc  = Vt + SB;
  u16* Wot = Cc + SB;
  // BT1/BT2 alias into Cc: written by prep, read by proj, then Cc is fully
  // overwritten by flash_k before gemm_o_k reads it (in-stream ordering).
  u16* BT1 = Cc;                        // 1536*1536 = 2359296 elems
  u16* BT2 = Cc + 2359296;              // 768*768   =  589824 elems

  prep_k<<<24000, 256, 0, stream>>>(x, Wq, Wk, Wv, Wo, Xh, Xl, BT1, BT2, Wot);
  proj_k<<<2304,  256, 0, stream>>>(Xh, Xl, BT1, BT2, Qh, Ql, Kh, Kl, Vt);
  flash_k<<<768,  512, 0, stream>>>(Qh, Ql, Kh, Kl, Vt, Cc);
  gemm_o_k<<<256, 256, 0, stream>>>(Cc, Wot, out);
}